// Round 12
// baseline (270.706 us; speedup 1.0000x reference)
//
#include <hip/hip_runtime.h>

#define NN 1024
#define NW 32            // u32 words per full 1024-bit row
#define KMAX 640         // max #non-roots (P(K>640) < 1e-14)
#define KW 10            // u64 words per compact row
#define KWP 11           // padded LDS row stride (u64)
#define INF_KEY 0x7FFFFFFFu
#define NOTFOUND_BASE (1u << 21)

typedef unsigned int u32;
typedef unsigned long long u64;
typedef unsigned short u16;

__device__ __forceinline__ u64 shflxor64(u64 v, int m) {
    return (u64)__shfl_xor((long long)v, m);
}
__device__ __forceinline__ u64 rdl64(u64 v, int s) {   // broadcast lane s (uniform s)
    u32 lo = (u32)__builtin_amdgcn_readlane((int)(u32)v, s);
    u32 hi = (u32)__builtin_amdgcn_readlane((int)(u32)(v >> 32), s);
    return ((u64)hi << 32) | (u64)lo;
}
__device__ __forceinline__ u64 transpose64(u64 x, int lane) {
    #pragma unroll
    for (int st = 32; st >= 1; st >>= 1) {
        u64 mlo = (st == 32) ? 0x00000000FFFFFFFFull :
                  (st == 16) ? 0x0000FFFF0000FFFFull :
                  (st == 8)  ? 0x00FF00FF00FF00FFull :
                  (st == 4)  ? 0x0F0F0F0F0F0F0F0Full :
                  (st == 2)  ? 0x3333333333333333ull : 0x5555555555555555ull;
        u64 y = shflxor64(x, st);
        x = ((lane & st) == 0) ? ((x & mlo) | ((y & mlo) << st))
                               : ((x & ~mlo) | ((y & ~mlo) >> st));
    }
    return x;
}

// ---- K1: edge hard bits -> E ----
__global__ void edge_bits_kernel(const float* __restrict__ ep, const float* __restrict__ ge,
                                 u32* __restrict__ E)
{
    int idx = blockIdx.x * blockDim.x + threadIdx.x;
    float p = ep[idx];
    float2 g = reinterpret_cast<const float2*>(ge)[idx];
    bool hard = (p + g.x) > ((1.0f - p) + g.y);
    u64 m = __ballot(hard);
    int lane = threadIdx.x & 63;
    if ((lane & 31) == 0) E[idx >> 5] = (u32)(m >> (lane & 32));
}

// ---- K2: roots + seed (transpose-free) -> posof / npl / meta ----
__global__ __launch_bounds__(1024) void seed_kernel(
    const float* __restrict__ rp, const float* __restrict__ gr,
    const u32* __restrict__ Eg, u32* __restrict__ meta_g,
    u16* __restrict__ posof_g, u16* __restrict__ npl_g)
{
    __shared__ u32 rootm[32], rootpre[32];
    __shared__ u32 key[NN];
    const int tid = threadIdx.x;
    const int lane = tid & 63;
    const int wid  = tid >> 6;

    float p0 = rp[tid];
    float2 g0 = reinterpret_cast<const float2*>(gr)[tid];
    bool isroot = (p0 + g0.x) > ((1.0f - p0) + g0.y);
    u64 rm = __ballot(isroot);
    if (lane == 0) { rootm[wid * 2] = (u32)rm; rootm[wid * 2 + 1] = (u32)(rm >> 32); }
    __syncthreads();
    if (tid == 0) {
        u32 s = 0;
        #pragma unroll
        for (int w = 0; w < 32; ++w) { rootpre[w] = s; s += __popc(rootm[w]); }
    }
    __syncthreads();

    // rank of first root hitting node tid (scan root rows of E; expected ~14 rows)
    int fr = -1;
    if (!isroot) {
        int rrank = 0;
        for (int i2 = 0; i2 < NN; ++i2) {
            if ((rootm[i2 >> 5] >> (i2 & 31)) & 1u) {
                u32 wv = Eg[(size_t)i2 * NW + (tid >> 5)];
                if (fr < 0 && ((wv >> (tid & 31)) & 1u)) fr = rrank;
                ++rrank;
                if (__all(fr >= 0)) break;       // exec-masked: nonroot lanes only
            }
        }
    }
    u32 mykey = isroot ? INF_KEY
                       : (fr >= 0 ? (((u32)fr << 10) | (u32)tid) : (NOTFOUND_BASE | (u32)tid));
    key[tid] = mykey;
    __syncthreads();

    int pos = 0, tl = 0, Kc = 0;
    {
        const uint4* k4 = (const uint4*)key;
        for (int q = 0; q < 256; ++q) {
            uint4 kk = k4[q];
            pos += (kk.x < mykey) + (kk.y < mykey) + (kk.z < mykey) + (kk.w < mykey);
            tl  += (kk.x < NOTFOUND_BASE) + (kk.y < NOTFOUND_BASE) + (kk.z < NOTFOUND_BASE) + (kk.w < NOTFOUND_BASE);
            Kc  += (kk.x != INF_KEY) + (kk.y != INF_KEY) + (kk.z != INF_KEY) + (kk.w != INF_KEY);
        }
    }
    if (!isroot && pos < KMAX) npl_g[pos] = (u16)tid;
    posof_g[tid] = isroot ? (u16)0xFFFF : (u16)pos;
    if (tid == 0) {
        meta_g[0] = (u32)min(tl, KMAX);
        meta_g[1] = (u32)min(Kc, KMAX);
    }
}

// ---- K3: queue-permuted compact bit matrix Bq[s][t] = E[node(s)][node(t)] ----
__global__ __launch_bounds__(256) void compactB_kernel(
    const u32* __restrict__ E, const u16* __restrict__ npl_g,
    const u32* __restrict__ meta_g, u64* __restrict__ Bq_g)
{
    __shared__ u16 npL[KMAX];
    const int tid = threadIdx.x;
    for (int k = tid; k < KMAX; k += 256) npL[k] = npl_g[k];
    u32 K = meta_g[1];
    __syncthreads();
    int gid = blockIdx.x * 256 + tid;        // s*KW + w
    int s = gid / KW, w = gid - s * KW;
    if (s >= (int)K) return;
    const u32* row = E + (u32)npL[s] * NW;
    u64 acc = 0;
    int cb = w * 64;
    for (int b = 0; b < 64; ++b) {
        int t = cb + b;
        if (t < (int)K) {
            int j = npL[t];
            acc |= ((u64)((row[j >> 5] >> (j & 31)) & 1u)) << b;
        }
    }
    Bq_g[gid] = acc;
}

// ---- K4: blocked closure; readlane serial + readlane near/far (no LDS gather) ----
__global__ __launch_bounds__(1024) void bfs_closure(
    u64* __restrict__ Bq_g, const u32* __restrict__ meta_g)
{
    extern __shared__ u64 sm[];
    u64* A   = sm;                    // KMAX*KWP
    u64* BqL = A + KMAX * KWP;        // KMAX*KWP (edge rows -> dag rows in place)

    const int tid  = threadIdx.x;
    const int lane = tid & 63;
    const int wid  = tid >> 6;
    const int tail = (int)meta_g[0];
    const int nb   = (tail + 63) >> 6;

    for (int it = tid; it < tail * KW; it += 1024) {
        int r = it / KW, w = it - r * KW;
        BqL[r * KWP + w] = Bq_g[it];
    }
    for (int it = tid; it < tail * KWP; it += 1024) {
        int r = it / KWP, w = it - r * KWP;
        A[it] = (w == (r >> 6)) ? (1ull << (r & 63)) : 0ull;
    }
    __syncthreads();

    auto serial_block = [&](int p) {
        const int b0 = p << 6;
        const int rem = min(64, tail - b0);
        const int sp = b0 + lane;
        const bool valid = lane < rem;
        int wph[KW];
        #pragma unroll
        for (int w = 0; w < KW; ++w) { int ww = w + p; wph[w] = (ww >= KW) ? ww - KW : ww; }
        u64 a[KW], b[KW];
        #pragma unroll
        for (int w = 0; w < KW; ++w) {
            a[w] = valid ? A[sp * KWP + wph[w]]   : 0ull;
            b[w] = valid ? BqL[sp * KWP + wph[w]] : 0ull;
        }
        const u64 Dg = b[0];
        #pragma unroll 64
        for (int s = 0; s < 64; ++s) {
            u64 hrow = rdl64(Dg & ~a[0], s);
            if (hrow) {
                bool h = (((hrow >> lane) & 1ull) != 0ull) && (lane > s);
                u64 hm = h ? ~0ull : 0ull;
                #pragma unroll
                for (int w = 0; w < KW; ++w) a[w] |= rdl64(a[w], s) & hm;
            }
        }
        if (valid) {
            #pragma unroll
            for (int w = 0; w < KW; ++w) {
                A[sp * KWP + wph[w]]   = a[w];
                BqL[sp * KWP + wph[w]] = b[w] & ~a[w];
            }
        }
    };

    // near(ps): sources block ps -> targets block ps+1; one word per worker wave
    auto near_cross = [&](int ps) {
        if ((wid & 3) == 0) return;                   // keep SIMD0 clear
        int widx = wid - 1 - (wid >> 2);              // 0..11
        if (widx >= KW) return;
        const int sb0 = ps << 6;
        const int b0t = sb0 + 64;
        if (b0t >= tail) return;
        u64 a_w = A[(sb0 + lane) * KWP + widx];       // lane s <-> source row s
        u64 x = transpose64(BqL[(sb0 + lane) * KWP + (b0t >> 6)], lane);
        int t = b0t + lane;
        if (t >= tail) x = 0;
        u64 acc = 0;
        #pragma unroll 64
        for (int s = 0; s < 64; ++s) {
            if (__any((x >> s) & 1ull)) {
                u64 hm = ((x >> s) & 1ull) ? ~0ull : 0ull;
                acc |= rdl64(a_w, s) & hm;
            }
        }
        if (t < tail && acc) A[t * KWP + widx] |= acc;
    };

    // far(ps): sources block ps -> target block ps+2+widx; full rows per wave
    auto far_cross = [&](int ps) {
        if ((wid & 3) == 0) return;                   // SIMDs 1-3 only
        int widx = wid - 1 - (wid >> 2);
        const int sb0 = ps << 6;
        const int t0 = sb0 + 128 + (widx << 6);
        if (t0 >= tail) return;
        u64 asrc[KW];
        #pragma unroll
        for (int w = 0; w < KW; ++w) asrc[w] = A[(sb0 + lane) * KWP + w];
        u64 x = transpose64(BqL[(sb0 + lane) * KWP + (t0 >> 6)], lane);
        int t = t0 + lane;
        if (t >= tail) x = 0;
        u64 acc[KW];
        #pragma unroll
        for (int w = 0; w < KW; ++w) acc[w] = 0ull;
        #pragma unroll 64
        for (int s = 0; s < 64; ++s) {
            if (__any((x >> s) & 1ull)) {
                u64 hm = ((x >> s) & 1ull) ? ~0ull : 0ull;
                #pragma unroll
                for (int w = 0; w < KW; ++w) acc[w] |= rdl64(asrc[w], s) & hm;
            }
        }
        if (t < tail) {
            u64* At = A + (size_t)t * KWP;
            #pragma unroll
            for (int w = 0; w < KW; ++w) At[w] |= acc[w];
        }
    };

    if (nb > 0) {
        if (wid == 0) {
            __builtin_amdgcn_s_setprio(1); serial_block(0); __builtin_amdgcn_s_setprio(0);
        }
        __syncthreads();
        for (int p = 1; p < nb; ++p) {
            near_cross(p - 1);
            __syncthreads();
            if (wid == 0) {
                __builtin_amdgcn_s_setprio(1); serial_block(p); __builtin_amdgcn_s_setprio(0);
            } else {
                far_cross(p - 1);
            }
            __syncthreads();
        }
    }
    __syncthreads();
    for (int it = tid; it < tail * KW; it += 1024) {
        int r = it / KW, w = it - r * KW;
        Bq_g[it] = BqL[r * KWP + w];
    }
}

// ---- K5: expand to f32 output ----
__global__ __launch_bounds__(256) void final_expand(
    const u32* __restrict__ E, const u64* __restrict__ Bq_g,
    const u16* __restrict__ posof_g, const u32* __restrict__ meta_g,
    float4* __restrict__ out)
{
    int gid = blockIdx.x * 256 + threadIdx.x;
    int i = gid >> 8;
    int j0 = (gid & 255) << 2;
    u32 tail = meta_g[0];
    u32 pi = posof_g[i];
    float r[4] = {0.f, 0.f, 0.f, 0.f};
    if (pi == 0xFFFFu) {                              // root row: E & ~root & ~self
        u32 wv = E[(size_t)i * NW + (j0 >> 5)];
        #pragma unroll
        for (int t = 0; t < 4; ++t) {
            u32 pj = posof_g[j0 + t];
            bool nz = ((wv >> ((j0 & 31) + t)) & 1u) && (pj != 0xFFFFu);
            r[t] = nz ? 1.0f : 0.0f;
        }
    } else if (pi < tail) {                           // processed nonroot row
        const u64* row = Bq_g + (size_t)pi * KW;
        #pragma unroll
        for (int t = 0; t < 4; ++t) {
            u32 pj = posof_g[j0 + t];
            if (pj != 0xFFFFu && pj < (u32)KMAX) {
                u64 wv = row[pj >> 6];
                r[t] = ((wv >> (pj & 63)) & 1ull) ? 1.0f : 0.0f;
            }
        }
    }
    out[gid] = make_float4(r[0], r[1], r[2], r[3]);
}

extern "C" void kernel_launch(void* const* d_in, const int* in_sizes, int n_in,
                              void* d_out, int out_size, void* d_ws, size_t ws_size,
                              hipStream_t stream) {
    const float* root_probs = (const float*)d_in[0];
    const float* edge_probs = (const float*)d_in[1];
    const float* g_roots    = (const float*)d_in[2];
    const float* g_edges    = (const float*)d_in[3];

    char* ws = (char*)d_ws;
    u32* E       = (u32*)(ws);                 // 131072 B
    u64* Bq_g    = (u64*)(ws + 131072);        // 51200 B
    u16* posof_g = (u16*)(ws + 182272);        // 2048 B
    u16* npl_g   = (u16*)(ws + 184320);        // 1280 B
    u32* meta_g  = (u32*)(ws + 185600);        // 64 B

    edge_bits_kernel<<<NN * NN / 256, 256, 0, stream>>>(edge_probs, g_edges, E);
    seed_kernel<<<1, NN, 0, stream>>>(root_probs, g_roots, E, meta_g, posof_g, npl_g);
    compactB_kernel<<<(KMAX * KW + 255) / 256, 256, 0, stream>>>(E, npl_g, meta_g, Bq_g);

    size_t lds = (size_t)KMAX * KWP * 8 * 2;   // 112640 B
    hipFuncSetAttribute((const void*)bfs_closure,
                        hipFuncAttributeMaxDynamicSharedMemorySize, (int)lds);
    bfs_closure<<<1, NN, lds, stream>>>(Bq_g, meta_g);

    final_expand<<<NN * NN / 4 / 256, 256, 0, stream>>>(E, Bq_g, posof_g, meta_g,
                                                        (float4*)d_out);
}

// Round 13
// 215.964 us; speedup vs baseline: 1.2535x; 1.2535x over previous
//
#include <hip/hip_runtime.h>

#define NN 1024
#define NW 32            // u32 words per full 1024-bit row
#define KMAX 640         // max #non-roots (P(K>640) < 1e-14)
#define KW 10            // u64 words per compact row
#define KWP 11           // BqL LDS row stride (u64)
#define AP  14           // A LDS row stride (u64): 112 B, 16-aligned for b128
#define INF_KEY 0x7FFFFFFFu
#define NOTFOUND_BASE (1u << 21)

typedef unsigned int u32;
typedef unsigned long long u64;
typedef unsigned short u16;

__device__ __forceinline__ u64 shflxor64(u64 v, int m) {
    return (u64)__shfl_xor((long long)v, m);
}
__device__ __forceinline__ u64 rdl64(u64 v, int s) {   // broadcast lane s (uniform s)
    u32 lo = (u32)__builtin_amdgcn_readlane((int)(u32)v, s);
    u32 hi = (u32)__builtin_amdgcn_readlane((int)(u32)(v >> 32), s);
    return ((u64)hi << 32) | (u64)lo;
}
__device__ __forceinline__ u64 transpose64(u64 x, int lane) {
    #pragma unroll
    for (int st = 32; st >= 1; st >>= 1) {
        u64 mlo = (st == 32) ? 0x00000000FFFFFFFFull :
                  (st == 16) ? 0x0000FFFF0000FFFFull :
                  (st == 8)  ? 0x00FF00FF00FF00FFull :
                  (st == 4)  ? 0x0F0F0F0F0F0F0F0Full :
                  (st == 2)  ? 0x3333333333333333ull : 0x5555555555555555ull;
        u64 y = shflxor64(x, st);
        x = ((lane & st) == 0) ? ((x & mlo) | ((y & mlo) << st))
                               : ((x & ~mlo) | ((y & ~mlo) >> st));
    }
    return x;
}

// ---- K1: edge hard bits -> E ----
__global__ void edge_bits_kernel(const float* __restrict__ ep, const float* __restrict__ ge,
                                 u32* __restrict__ E)
{
    int idx = blockIdx.x * blockDim.x + threadIdx.x;
    float p = ep[idx];
    float2 g = reinterpret_cast<const float2*>(ge)[idx];
    bool hard = (p + g.x) > ((1.0f - p) + g.y);
    u64 m = __ballot(hard);
    int lane = threadIdx.x & 63;
    if ((lane & 31) == 0) E[idx >> 5] = (u32)(m >> (lane & 32));
}

// ---- K2: roots + seed (transpose-free) -> posof / npl / meta ----
__global__ __launch_bounds__(1024) void seed_kernel(
    const float* __restrict__ rp, const float* __restrict__ gr,
    const u32* __restrict__ Eg, u32* __restrict__ meta_g,
    u16* __restrict__ posof_g, u16* __restrict__ npl_g)
{
    __shared__ u32 rootm[32], rootpre[32];
    __shared__ u32 key[NN];
    const int tid = threadIdx.x;
    const int lane = tid & 63;
    const int wid  = tid >> 6;

    float p0 = rp[tid];
    float2 g0 = reinterpret_cast<const float2*>(gr)[tid];
    bool isroot = (p0 + g0.x) > ((1.0f - p0) + g0.y);
    u64 rm = __ballot(isroot);
    if (lane == 0) { rootm[wid * 2] = (u32)rm; rootm[wid * 2 + 1] = (u32)(rm >> 32); }
    __syncthreads();
    if (tid == 0) {
        u32 s = 0;
        #pragma unroll
        for (int w = 0; w < 32; ++w) { rootpre[w] = s; s += __popc(rootm[w]); }
    }
    __syncthreads();

    int fr = -1;
    if (!isroot) {
        int rrank = 0;
        for (int i2 = 0; i2 < NN; ++i2) {
            if ((rootm[i2 >> 5] >> (i2 & 31)) & 1u) {
                u32 wv = Eg[(size_t)i2 * NW + (tid >> 5)];
                if (fr < 0 && ((wv >> (tid & 31)) & 1u)) fr = rrank;
                ++rrank;
                if (__all(fr >= 0)) break;
            }
        }
    }
    u32 mykey = isroot ? INF_KEY
                       : (fr >= 0 ? (((u32)fr << 10) | (u32)tid) : (NOTFOUND_BASE | (u32)tid));
    key[tid] = mykey;
    __syncthreads();

    int pos = 0, tl = 0, Kc = 0;
    {
        const uint4* k4 = (const uint4*)key;
        for (int q = 0; q < 256; ++q) {
            uint4 kk = k4[q];
            pos += (kk.x < mykey) + (kk.y < mykey) + (kk.z < mykey) + (kk.w < mykey);
            tl  += (kk.x < NOTFOUND_BASE) + (kk.y < NOTFOUND_BASE) + (kk.z < NOTFOUND_BASE) + (kk.w < NOTFOUND_BASE);
            Kc  += (kk.x != INF_KEY) + (kk.y != INF_KEY) + (kk.z != INF_KEY) + (kk.w != INF_KEY);
        }
    }
    if (!isroot && pos < KMAX) npl_g[pos] = (u16)tid;
    posof_g[tid] = isroot ? (u16)0xFFFF : (u16)pos;
    if (tid == 0) {
        meta_g[0] = (u32)min(tl, KMAX);
        meta_g[1] = (u32)min(Kc, KMAX);
    }
}

// ---- K3: queue-permuted compact bit matrix Bq[s][t] = E[node(s)][node(t)] ----
__global__ __launch_bounds__(256) void compactB_kernel(
    const u32* __restrict__ E, const u16* __restrict__ npl_g,
    const u32* __restrict__ meta_g, u64* __restrict__ Bq_g)
{
    __shared__ u16 npL[KMAX];
    const int tid = threadIdx.x;
    for (int k = tid; k < KMAX; k += 256) npL[k] = npl_g[k];
    u32 K = meta_g[1];
    __syncthreads();
    int gid = blockIdx.x * 256 + tid;        // s*KW + w
    int s = gid / KW, w = gid - s * KW;
    if (s >= (int)K) return;
    const u32* row = E + (u32)npL[s] * NW;
    u64 acc = 0;
    int cb = w * 64;
    for (int b = 0; b < 64; ++b) {
        int t = cb + b;
        if (t < (int)K) {
            int j = npL[t];
            acc |= ((u64)((row[j >> 5] >> (j & 31)) & 1u)) << b;
        }
    }
    Bq_g[gid] = acc;
}

// ---- K4: blocked closure; readlane serial + sparse b128-gather near/far ----
__global__ __launch_bounds__(1024) void bfs_closure(
    u64* __restrict__ Bq_g, const u32* __restrict__ meta_g)
{
    extern __shared__ u64 sm[];
    u64* A   = sm;                    // KMAX*AP   (112-B rows, 16-aligned)
    u64* BqL = A + KMAX * AP;         // KMAX*KWP  (edge rows -> dag rows in place)

    const int tid  = threadIdx.x;
    const int lane = tid & 63;
    const int wid  = tid >> 6;
    const int tail = (int)meta_g[0];
    const int nb   = (tail + 63) >> 6;

    for (int it = tid; it < tail * KW; it += 1024) {
        int r = it / KW, w = it - r * KW;
        BqL[r * KWP + w] = Bq_g[it];
    }
    for (int it = tid; it < tail * AP; it += 1024) {
        int r = it / AP, w = it - r * AP;
        A[it] = (w == (r >> 6)) ? (1ull << (r & 63)) : 0ull;   // pad words -> 0
    }
    __syncthreads();

    auto serial_block = [&](int p) {
        const int b0 = p << 6;
        const int rem = min(64, tail - b0);
        const int sp = b0 + lane;
        const bool valid = lane < rem;
        int wph[KW];
        #pragma unroll
        for (int w = 0; w < KW; ++w) { int ww = w + p; wph[w] = (ww >= KW) ? ww - KW : ww; }
        u64 a[KW], b[KW];
        #pragma unroll
        for (int w = 0; w < KW; ++w) {
            a[w] = valid ? A[sp * AP + wph[w]]    : 0ull;
            b[w] = valid ? BqL[sp * KWP + wph[w]] : 0ull;
        }
        const u64 Dg = b[0];
        #pragma unroll 64
        for (int s = 0; s < 64; ++s) {
            u64 hrow = rdl64(Dg & ~a[0], s);
            if (hrow) {
                bool h = (((hrow >> lane) & 1ull) != 0ull) && (lane > s);
                u64 hm = h ? ~0ull : 0ull;
                #pragma unroll
                for (int w = 0; w < KW; ++w) a[w] |= rdl64(a[w], s) & hm;
            }
        }
        if (valid) {
            #pragma unroll
            for (int w = 0; w < KW; ++w) {
                A[sp * AP + wph[w]]    = a[w];
                BqL[sp * KWP + wph[w]] = b[w] & ~a[w];
            }
        }
    };

    // near(ps): sources block ps -> targets block ps+1; word wid per wave (waves 0..KW-1)
    auto near_cross = [&](int ps) {
        if (wid >= KW) return;
        const int sb0 = ps << 6;
        const int b0t = sb0 + 64;
        if (b0t >= tail) return;
        u64 x = transpose64(BqL[(sb0 + lane) * KWP + (b0t >> 6)], lane);
        int t = b0t + lane;
        if (t >= tail) x = 0;
        if (x) {
            u64 acc = 0, m = x;
            while (m) {
                int s = __ffsll((long long)m) - 1; m &= m - 1;
                acc |= A[(sb0 + s) * AP + wid];
            }
            A[t * AP + wid] |= acc;
        }
    };

    // far(ps): sources block ps -> target block ps+2+(wid-1); sparse b128 gathers
    auto far_cross = [&](int ps) {
        if (wid == 0) return;
        const int sb0 = ps << 6;
        const int t0 = sb0 + 128 + ((wid - 1) << 6);
        if (t0 >= tail) return;
        u64 x = transpose64(BqL[(sb0 + lane) * KWP + (t0 >> 6)], lane);
        int t = t0 + lane;
        if (t >= tail) x = 0;
        if (x) {
            ulonglong2 acc[5];
            #pragma unroll
            for (int k = 0; k < 5; ++k) { acc[k].x = 0ull; acc[k].y = 0ull; }
            u64 m = x;
            while (m) {
                int s = __ffsll((long long)m) - 1; m &= m - 1;
                const ulonglong2* Ar = (const ulonglong2*)(A + (size_t)(sb0 + s) * AP);
                #pragma unroll
                for (int k = 0; k < 5; ++k) {
                    ulonglong2 v = Ar[k];                 // ds_read_b128
                    acc[k].x |= v.x; acc[k].y |= v.y;
                }
            }
            ulonglong2* At = (ulonglong2*)(A + (size_t)t * AP);
            #pragma unroll
            for (int k = 0; k < 5; ++k) {
                ulonglong2 v = At[k];
                v.x |= acc[k].x; v.y |= acc[k].y;
                At[k] = v;                                // ds_write_b128
            }
        }
    };

    if (nb > 0) {
        if (wid == 0) {
            __builtin_amdgcn_s_setprio(1); serial_block(0); __builtin_amdgcn_s_setprio(0);
        }
        __syncthreads();
        for (int p = 1; p < nb; ++p) {
            near_cross(p - 1);
            __syncthreads();
            if (wid == 0) {
                __builtin_amdgcn_s_setprio(1); serial_block(p); __builtin_amdgcn_s_setprio(0);
            } else {
                far_cross(p - 1);
            }
            __syncthreads();
        }
    }
    __syncthreads();
    for (int it = tid; it < tail * KW; it += 1024) {
        int r = it / KW, w = it - r * KW;
        Bq_g[it] = BqL[r * KWP + w];
    }
}

// ---- K5: expand to f32 output ----
__global__ __launch_bounds__(256) void final_expand(
    const u32* __restrict__ E, const u64* __restrict__ Bq_g,
    const u16* __restrict__ posof_g, const u32* __restrict__ meta_g,
    float4* __restrict__ out)
{
    int gid = blockIdx.x * 256 + threadIdx.x;
    int i = gid >> 8;
    int j0 = (gid & 255) << 2;
    u32 tail = meta_g[0];
    u32 pi = posof_g[i];
    float r[4] = {0.f, 0.f, 0.f, 0.f};
    if (pi == 0xFFFFu) {                              // root row: E & ~root & ~self
        u32 wv = E[(size_t)i * NW + (j0 >> 5)];
        #pragma unroll
        for (int t = 0; t < 4; ++t) {
            u32 pj = posof_g[j0 + t];
            bool nz = ((wv >> ((j0 & 31) + t)) & 1u) && (pj != 0xFFFFu);
            r[t] = nz ? 1.0f : 0.0f;
        }
    } else if (pi < tail) {                           // processed nonroot row
        const u64* row = Bq_g + (size_t)pi * KW;
        #pragma unroll
        for (int t = 0; t < 4; ++t) {
            u32 pj = posof_g[j0 + t];
            if (pj != 0xFFFFu && pj < (u32)KMAX) {
                u64 wv = row[pj >> 6];
                r[t] = ((wv >> (pj & 63)) & 1ull) ? 1.0f : 0.0f;
            }
        }
    }
    out[gid] = make_float4(r[0], r[1], r[2], r[3]);
}

extern "C" void kernel_launch(void* const* d_in, const int* in_sizes, int n_in,
                              void* d_out, int out_size, void* d_ws, size_t ws_size,
                              hipStream_t stream) {
    const float* root_probs = (const float*)d_in[0];
    const float* edge_probs = (const float*)d_in[1];
    const float* g_roots    = (const float*)d_in[2];
    const float* g_edges    = (const float*)d_in[3];

    char* ws = (char*)d_ws;
    u32* E       = (u32*)(ws);                 // 131072 B
    u64* Bq_g    = (u64*)(ws + 131072);        // 51200 B
    u16* posof_g = (u16*)(ws + 182272);        // 2048 B
    u16* npl_g   = (u16*)(ws + 184320);        // 1280 B
    u32* meta_g  = (u32*)(ws + 185600);        // 64 B

    edge_bits_kernel<<<NN * NN / 256, 256, 0, stream>>>(edge_probs, g_edges, E);
    seed_kernel<<<1, NN, 0, stream>>>(root_probs, g_roots, E, meta_g, posof_g, npl_g);
    compactB_kernel<<<(KMAX * KW + 255) / 256, 256, 0, stream>>>(E, npl_g, meta_g, Bq_g);

    size_t lds = (size_t)KMAX * AP * 8 + (size_t)KMAX * KWP * 8;   // 128000 B
    hipFuncSetAttribute((const void*)bfs_closure,
                        hipFuncAttributeMaxDynamicSharedMemorySize, (int)lds);
    bfs_closure<<<1, NN, lds, stream>>>(Bq_g, meta_g);

    final_expand<<<NN * NN / 4 / 256, 256, 0, stream>>>(E, Bq_g, posof_g, meta_g,
                                                        (float4*)d_out);
}

// Round 14
// 177.951 us; speedup vs baseline: 1.5212x; 1.2136x over previous
//
#include <hip/hip_runtime.h>

#define NN 1024
#define NW 32            // u32 words per full 1024-bit row
#define KMAX 640         // max #non-roots (P(K>640) < 1e-14)
#define KW 10            // u64 words per compact row
#define AP  14           // A LDS row stride (u64): 112 B, 16-aligned for b128
#define BTP 11           // BT LDS row stride (u64)
#define INF_KEY 0x7FFFFFFFu
#define NOTFOUND_BASE (1u << 21)

typedef unsigned int u32;
typedef unsigned long long u64;
typedef unsigned short u16;

__device__ __forceinline__ u64 rdl64(u64 v, int s) {   // broadcast lane s (uniform s)
    u32 lo = (u32)__builtin_amdgcn_readlane((int)(u32)v, s);
    u32 hi = (u32)__builtin_amdgcn_readlane((int)(u32)(v >> 32), s);
    return ((u64)hi << 32) | (u64)lo;
}

// ---- K1: edge hard bits -> E ----
__global__ void edge_bits_kernel(const float* __restrict__ ep, const float* __restrict__ ge,
                                 u32* __restrict__ E)
{
    int idx = blockIdx.x * blockDim.x + threadIdx.x;
    float p = ep[idx];
    float2 g = reinterpret_cast<const float2*>(ge)[idx];
    bool hard = (p + g.x) > ((1.0f - p) + g.y);
    u64 m = __ballot(hard);
    int lane = threadIdx.x & 63;
    if ((lane & 31) == 0) E[idx >> 5] = (u32)(m >> (lane & 32));
}

// ---- K2: roots + seed (transpose-free) -> posof / npl / meta ----
__global__ __launch_bounds__(1024) void seed_kernel(
    const float* __restrict__ rp, const float* __restrict__ gr,
    const u32* __restrict__ Eg, u32* __restrict__ meta_g,
    u16* __restrict__ posof_g, u16* __restrict__ npl_g)
{
    __shared__ u32 rootm[32], rootpre[32];
    __shared__ u32 key[NN];
    const int tid = threadIdx.x;
    const int lane = tid & 63;
    const int wid  = tid >> 6;

    float p0 = rp[tid];
    float2 g0 = reinterpret_cast<const float2*>(gr)[tid];
    bool isroot = (p0 + g0.x) > ((1.0f - p0) + g0.y);
    u64 rm = __ballot(isroot);
    if (lane == 0) { rootm[wid * 2] = (u32)rm; rootm[wid * 2 + 1] = (u32)(rm >> 32); }
    __syncthreads();
    if (tid == 0) {
        u32 s = 0;
        #pragma unroll
        for (int w = 0; w < 32; ++w) { rootpre[w] = s; s += __popc(rootm[w]); }
    }
    __syncthreads();

    int fr = -1;
    if (!isroot) {
        int rrank = 0;
        for (int i2 = 0; i2 < NN; ++i2) {
            if ((rootm[i2 >> 5] >> (i2 & 31)) & 1u) {
                u32 wv = Eg[(size_t)i2 * NW + (tid >> 5)];
                if (fr < 0 && ((wv >> (tid & 31)) & 1u)) fr = rrank;
                ++rrank;
                if (__all(fr >= 0)) break;
            }
        }
    }
    u32 mykey = isroot ? INF_KEY
                       : (fr >= 0 ? (((u32)fr << 10) | (u32)tid) : (NOTFOUND_BASE | (u32)tid));
    key[tid] = mykey;
    __syncthreads();

    int pos = 0, tl = 0, Kc = 0;
    {
        const uint4* k4 = (const uint4*)key;
        for (int q = 0; q < 256; ++q) {
            uint4 kk = k4[q];
            pos += (kk.x < mykey) + (kk.y < mykey) + (kk.z < mykey) + (kk.w < mykey);
            tl  += (kk.x < NOTFOUND_BASE) + (kk.y < NOTFOUND_BASE) + (kk.z < NOTFOUND_BASE) + (kk.w < NOTFOUND_BASE);
            Kc  += (kk.x != INF_KEY) + (kk.y != INF_KEY) + (kk.z != INF_KEY) + (kk.w != INF_KEY);
        }
    }
    if (!isroot && pos < KMAX) npl_g[pos] = (u16)tid;
    posof_g[tid] = isroot ? (u16)0xFFFF : (u16)pos;
    if (tid == 0) {
        meta_g[0] = (u32)min(tl, KMAX);
        meta_g[1] = (u32)min(Kc, KMAX);
    }
}

// ---- K3: BT[t][w'] bit s = B[w'*64+s][t] = E[node(w'*64+s)][node(t)] ----
__global__ __launch_bounds__(256) void transposeB_kernel(
    const u32* __restrict__ E, const u16* __restrict__ npl_g,
    const u32* __restrict__ meta_g, u64* __restrict__ BT_g)
{
    __shared__ u16 npL[KMAX];
    const int tid = threadIdx.x;
    for (int k = tid; k < KMAX; k += 256) npL[k] = npl_g[k];
    u32 tail = meta_g[0];
    __syncthreads();
    int gid = blockIdx.x * 256 + tid;        // t*KW + w
    int t = gid / KW, w = gid - t * KW;
    if (t >= (int)tail) return;
    int jt = npL[t];
    u64 acc = 0;
    int cb = w * 64;
    for (int b = 0; b < 64; ++b) {
        int s = cb + b;
        if (s < (int)tail) {
            int is = npL[s];
            acc |= ((u64)((E[(size_t)is * NW + (jt >> 5)] >> (jt & 31)) & 1u)) << b;
        }
    }
    BT_g[gid] = acc;
}

// ---- K4: upper-triangular transitive closure (static hits from BT) ----
template<int P>
__device__ __forceinline__ void diag_t(u64* A, const u64* BTL, int b0, int lane, int tail)
{
    const int t = b0 + lane;
    const bool valid = t < tail;
    u64 a[P + 1];
    #pragma unroll
    for (int w = 0; w <= P; ++w) a[w] = valid ? A[t * AP + w] : 0ull;
    u64 btw = valid ? BTL[t * BTP + P] : 0ull;     // static hit bits (in-block sources)
    #pragma unroll
    for (int s = 0; s < 63; ++s) {
        bool h = (((btw >> s) & 1ull) != 0ull) && (lane > s);
        u64 hm = h ? ~0ull : 0ull;
        #pragma unroll
        for (int w = 0; w <= P; ++w) a[w] |= rdl64(a[w], s) & hm;
    }
    if (valid) {
        #pragma unroll
        for (int w = 0; w <= P; ++w) A[t * AP + w] = a[w];
    }
}

__global__ __launch_bounds__(1024) void bfs_closure(
    const u64* __restrict__ BT_g, u64* __restrict__ A_g, const u32* __restrict__ meta_g)
{
    extern __shared__ u64 sm[];
    u64* A   = sm;                    // KMAX*AP  (71680 B)
    u64* BTL = A + KMAX * AP;         // KMAX*BTP (56320 B)

    const int tid  = threadIdx.x;
    const int lane = tid & 63;
    const int wid  = tid >> 6;
    const int tail = (int)meta_g[0];
    const int nb   = (tail + 63) >> 6;

    for (int r = tid; r < tail; r += 1024) {
        const u64* src = BT_g + (size_t)r * KW;
        u64* dst = BTL + (size_t)r * BTP;
        #pragma unroll
        for (int w = 0; w < KW; ++w) dst[w] = src[w];
    }
    for (int r = tid; r < tail; r += 1024) {
        u64* dst = A + (size_t)r * AP;
        #pragma unroll
        for (int w = 0; w < AP; ++w) dst[w] = 0ull;
        dst[r >> 6] = 1ull << (r & 63);
    }
    __syncthreads();

    auto diag_dispatch = [&](int p) {
        switch (p) {
            case 0: diag_t<0>(A, BTL, 0,       lane, tail); break;
            case 1: diag_t<1>(A, BTL, 64,      lane, tail); break;
            case 2: diag_t<2>(A, BTL, 128,     lane, tail); break;
            case 3: diag_t<3>(A, BTL, 192,     lane, tail); break;
            case 4: diag_t<4>(A, BTL, 256,     lane, tail); break;
            case 5: diag_t<5>(A, BTL, 320,     lane, tail); break;
            case 6: diag_t<6>(A, BTL, 384,     lane, tail); break;
            case 7: diag_t<7>(A, BTL, 448,     lane, tail); break;
            case 8: diag_t<8>(A, BTL, 512,     lane, tail); break;
            default: diag_t<9>(A, BTL, 576,    lane, tail); break;
        }
    };

    // near(p): sources block p-1 -> targets block p; word wid per wave (wid < p)
    auto near_cross = [&](int p) {
        if (wid >= p) return;
        const int sb0 = (p - 1) << 6;
        const int t = (p << 6) + lane;
        u64 x = (t < tail) ? BTL[(size_t)t * BTP + (p - 1)] : 0ull;
        if (!x) return;
        u64 acc = 0, m = x;
        while (m) {
            int s = __ffsll((long long)m) - 1; m &= m - 1;
            acc |= A[(size_t)(sb0 + s) * AP + wid];
        }
        A[(size_t)t * AP + wid] |= acc;
    };

    // far(p): sources block p-1 -> target blocks p+1..nb-1; 2 wave-halves per block
    auto far_cross = [&](int p) {
        const int sb0 = (p - 1) << 6;
        const int nbf = nb - 1 - p;
        if (nbf <= 0) return;
        const int W2 = (p + 1) >> 1;           // b128 slots covering words 0..p-1
        const int h0 = (W2 + 1) >> 1;
        for (int idx = wid - 1; idx < 2 * nbf; idx += 15) {
            const int tb = p + 1 + (idx >> 1);
            const int half = idx & 1;
            const int s0 = half ? h0 : 0;
            const int s1 = half ? W2 : h0;
            if (s0 >= s1) continue;
            const int t = (tb << 6) + lane;
            u64 x = (t < tail) ? BTL[(size_t)t * BTP + (p - 1)] : 0ull;
            if (!x) continue;
            ulonglong2 acc[5];
            #pragma unroll
            for (int k = 0; k < 5; ++k) { acc[k].x = 0ull; acc[k].y = 0ull; }
            u64 m = x;
            while (m) {
                int s = __ffsll((long long)m) - 1; m &= m - 1;
                const ulonglong2* Ar = (const ulonglong2*)(A + (size_t)(sb0 + s) * AP);
                #pragma unroll
                for (int k = 0; k < 5; ++k)
                    if (k >= s0 && k < s1) { ulonglong2 v = Ar[k]; acc[k].x |= v.x; acc[k].y |= v.y; }
            }
            ulonglong2* At = (ulonglong2*)(A + (size_t)t * AP);
            #pragma unroll
            for (int k = 0; k < 5; ++k)
                if (k >= s0 && k < s1) { ulonglong2 v = At[k]; v.x |= acc[k].x; v.y |= acc[k].y; At[k] = v; }
        }
    };

    if (nb > 0) {
        if (wid == 0) {
            __builtin_amdgcn_s_setprio(1); diag_dispatch(0); __builtin_amdgcn_s_setprio(0);
        }
        __syncthreads();
        for (int p = 1; p < nb; ++p) {
            near_cross(p);
            __syncthreads();
            if (wid == 0) {
                __builtin_amdgcn_s_setprio(1); diag_dispatch(p); __builtin_amdgcn_s_setprio(0);
            } else {
                far_cross(p);
            }
            __syncthreads();
        }
    }
    __syncthreads();
    for (int r = tid; r < tail; r += 1024) {
        const u64* src = A + (size_t)r * AP;
        u64* dst = A_g + (size_t)r * KW;
        #pragma unroll
        for (int w = 0; w < KW; ++w) dst[w] = src[w];
    }
}

// ---- K5: expand to f32 output (dag = E & masks & ~A) ----
__global__ __launch_bounds__(256) void final_expand(
    const u32* __restrict__ E, const u64* __restrict__ A_g,
    const u16* __restrict__ posof_g, const u32* __restrict__ meta_g,
    float4* __restrict__ out)
{
    int gid = blockIdx.x * 256 + threadIdx.x;
    int i = gid >> 8;
    int j0 = (gid & 255) << 2;
    u32 tail = meta_g[0];
    u32 pi = posof_g[i];
    float r[4] = {0.f, 0.f, 0.f, 0.f};
    if (pi == 0xFFFFu) {                              // root row: E & ~root (self excluded: i is root)
        u32 wv = E[(size_t)i * NW + (j0 >> 5)];
        #pragma unroll
        for (int t = 0; t < 4; ++t) {
            u32 pj = posof_g[j0 + t];
            bool nz = ((wv >> ((j0 & 31) + t)) & 1u) && (pj != 0xFFFFu);
            r[t] = nz ? 1.0f : 0.0f;
        }
    } else if (pi < tail) {                           // processed nonroot row
        const u64* Arow = A_g + (size_t)pi * KW;
        u32 wv = E[(size_t)i * NW + (j0 >> 5)];
        #pragma unroll
        for (int t = 0; t < 4; ++t) {
            u32 pj = posof_g[j0 + t];
            bool eb = (wv >> ((j0 & 31) + t)) & 1u;
            if (eb && pj != 0xFFFFu) {
                u64 ab = (pj < (u32)KMAX) ? Arow[pj >> 6] : 0ull;
                r[t] = ((ab >> (pj & 63)) & 1ull) ? 0.0f : 1.0f;
            }
        }
    }
    out[gid] = make_float4(r[0], r[1], r[2], r[3]);
}

extern "C" void kernel_launch(void* const* d_in, const int* in_sizes, int n_in,
                              void* d_out, int out_size, void* d_ws, size_t ws_size,
                              hipStream_t stream) {
    const float* root_probs = (const float*)d_in[0];
    const float* edge_probs = (const float*)d_in[1];
    const float* g_roots    = (const float*)d_in[2];
    const float* g_edges    = (const float*)d_in[3];

    char* ws = (char*)d_ws;
    u32* E       = (u32*)(ws);                 // 131072 B
    u64* BT_g    = (u64*)(ws + 131072);        // 51200 B
    u64* A_g     = (u64*)(ws + 182272);        // 51200 B
    u16* posof_g = (u16*)(ws + 233472);        // 2048 B
    u16* npl_g   = (u16*)(ws + 235520);        // 1280 B
    u32* meta_g  = (u32*)(ws + 236800);        // 64 B

    edge_bits_kernel<<<NN * NN / 256, 256, 0, stream>>>(edge_probs, g_edges, E);
    seed_kernel<<<1, NN, 0, stream>>>(root_probs, g_roots, E, meta_g, posof_g, npl_g);
    transposeB_kernel<<<(KMAX * KW + 255) / 256, 256, 0, stream>>>(E, npl_g, meta_g, BT_g);

    size_t lds = (size_t)KMAX * AP * 8 + (size_t)KMAX * BTP * 8;   // 128000 B
    hipFuncSetAttribute((const void*)bfs_closure,
                        hipFuncAttributeMaxDynamicSharedMemorySize, (int)lds);
    bfs_closure<<<1, NN, lds, stream>>>(BT_g, A_g, meta_g);

    final_expand<<<NN * NN / 4 / 256, 256, 0, stream>>>(E, A_g, posof_g, meta_g,
                                                        (float4*)d_out);
}

// Round 15
// 130.184 us; speedup vs baseline: 2.0794x; 1.3669x over previous
//
#include <hip/hip_runtime.h>

#define NN 1024
#define NW 32            // u32 words per full 1024-bit row
#define KMAX 640         // max #non-roots (P(K>640) < 1e-14)
#define KW 10            // u64 words per compact row
#define AP  14           // A LDS row stride (u64): 112 B, 16-aligned for b128
#define BTP 11           // BT LDS row stride (u64)
#define NBIN 1024

typedef unsigned int u32;
typedef unsigned long long u64;
typedef unsigned short u16;

__device__ __forceinline__ u64 rdl64(u64 v, int s) {   // broadcast lane s (uniform s)
    u32 lo = (u32)__builtin_amdgcn_readlane((int)(u32)v, s);
    u32 hi = (u32)__builtin_amdgcn_readlane((int)(u32)(v >> 32), s);
    return ((u64)hi << 32) | (u64)lo;
}

// ---- K1: edge hard bits -> E ----
__global__ void edge_bits_kernel(const float* __restrict__ ep, const float* __restrict__ ge,
                                 u32* __restrict__ E)
{
    int idx = blockIdx.x * blockDim.x + threadIdx.x;
    float p = ep[idx];
    float2 g = reinterpret_cast<const float2*>(ge)[idx];
    bool hard = (p + g.x) > ((1.0f - p) + g.y);
    u64 m = __ballot(hard);
    int lane = threadIdx.x & 63;
    if ((lane & 31) == 0) E[idx >> 5] = (u32)(m >> (lane & 32));
}

// ---- K2: roots + seed; histogram counting sort (stable by (rank, tid)) ----
__global__ __launch_bounds__(1024) void seed_kernel(
    const float* __restrict__ rp, const float* __restrict__ gr,
    const u32* __restrict__ Eg, u32* __restrict__ meta_g,
    u16* __restrict__ posof_g, u16* __restrict__ npl_g)
{
    extern __shared__ u32 sd[];
    u32* hist    = sd;                    // 16 * NBIN
    u32* scan    = hist + 16 * NBIN;      // NBIN (inclusive scan of totals)
    u32* rootm   = scan + NBIN;           // 32
    u32* rootpre = rootm + 32;            // 32

    const int tid = threadIdx.x;
    const int lane = tid & 63;
    const int wid  = tid >> 6;

    float p0 = rp[tid];
    float2 g0 = reinterpret_cast<const float2*>(gr)[tid];
    bool isroot = (p0 + g0.x) > ((1.0f - p0) + g0.y);
    u64 rm = __ballot(isroot);
    if (lane == 0) { rootm[wid * 2] = (u32)rm; rootm[wid * 2 + 1] = (u32)(rm >> 32); }
    for (int i = tid; i < 16 * NBIN; i += 1024) hist[i] = 0u;
    __syncthreads();
    if (tid == 0) {
        u32 s = 0;
        #pragma unroll
        for (int w = 0; w < 32; ++w) { rootpre[w] = s; s += __popc(rootm[w]); }
    }
    __syncthreads();

    // rank of first root hitting node tid (scan root rows of E; expected ~16 rows)
    int fr = -1;
    if (!isroot) {
        int rrank = 0;
        for (int i2 = 0; i2 < NN; ++i2) {
            if ((rootm[i2 >> 5] >> (i2 & 31)) & 1u) {
                u32 wv = Eg[(size_t)i2 * NW + (tid >> 5)];
                if (fr < 0 && ((wv >> (tid & 31)) & 1u)) fr = rrank;
                ++rrank;
                if (__all(fr >= 0)) break;
            }
        }
    }
    bool found = (!isroot) && (fr >= 0);
    u32 ridx = found ? (u32)fr : 0xFFFFFFFFu;

    if (found) atomicAdd(&hist[wid * NBIN + ridx], 1u);
    __syncthreads();

    // totals per bin
    for (int r = tid; r < NBIN; r += 1024) {
        u32 s = 0;
        #pragma unroll
        for (int w = 0; w < 16; ++w) s += hist[w * NBIN + r];
        scan[r] = s;
    }
    __syncthreads();
    // inclusive Hillis-Steele scan over NBIN
    for (int off = 1; off < NBIN; off <<= 1) {
        u32 v = 0;
        if (tid < NBIN && tid >= off) v = scan[tid - off];
        __syncthreads();
        if (tid < NBIN) scan[tid] += v;
        __syncthreads();
    }

    // stable intra-wave index among equal ranks (readlane loop)
    int intra = 0;
    #pragma unroll 64
    for (int l2 = 0; l2 < 64; ++l2) {
        u32 rr = (u32)__builtin_amdgcn_readlane((int)ridx, l2);
        intra += (rr == ridx && l2 < lane) ? 1 : 0;
    }
    u32 pos = 0;
    if (found) {
        u32 base = (ridx > 0) ? scan[ridx - 1] : 0u;
        u32 wb = 0;
        for (int w = 0; w < wid; ++w) wb += hist[w * NBIN + ridx];
        pos = base + wb + (u32)intra;
        if (pos < KMAX) npl_g[pos] = (u16)tid;
    }
    posof_g[tid] = isroot ? (u16)0xFFFF : (found ? (u16)pos : (u16)1023);
    if (tid == 0) {
        u32 tl = scan[NBIN - 1];                      // count of found nonroots
        meta_g[0] = (tl < (u32)KMAX) ? tl : (u32)KMAX;
    }
}

// ---- K3: BT[t][w'] bit s = E[node(w'*64+s)][node(t)] ----
__global__ __launch_bounds__(256) void transposeB_kernel(
    const u32* __restrict__ E, const u16* __restrict__ npl_g,
    const u32* __restrict__ meta_g, u64* __restrict__ BT_g)
{
    __shared__ u16 npL[KMAX];
    const int tid = threadIdx.x;
    for (int k = tid; k < KMAX; k += 256) npL[k] = npl_g[k];
    u32 tail = meta_g[0];
    __syncthreads();
    int gid = blockIdx.x * 256 + tid;        // t*KW + w
    int t = gid / KW, w = gid - t * KW;
    if (t >= (int)tail) return;
    int jt = npL[t];
    u64 acc = 0;
    int cb = w * 64;
    for (int b = 0; b < 64; ++b) {
        int s = cb + b;
        if (s < (int)tail) {
            int is = npL[s];
            acc |= ((u64)((E[(size_t)is * NW + (jt >> 5)] >> (jt & 31)) & 1u)) << b;
        }
    }
    BT_g[gid] = acc;
}

// ---- K4: upper-triangular transitive closure (static hits from BT) ----
template<int P>
__device__ __forceinline__ void diag_t(u64* A, const u64* BTL, int b0, int lane, int tail)
{
    const int t = b0 + lane;
    const bool valid = t < tail;
    u64 a[P + 1];
    #pragma unroll
    for (int w = 0; w <= P; ++w) a[w] = valid ? A[t * AP + w] : 0ull;
    u64 btw = valid ? BTL[t * BTP + P] : 0ull;
    btw &= (1ull << lane) - 1ull;                  // only sources s < lane matter
    #pragma unroll
    for (int s = 0; s < 63; ++s) {
        u64 hm = ((btw >> s) & 1ull) ? ~0ull : 0ull;
        #pragma unroll
        for (int w = 0; w <= P; ++w) a[w] |= rdl64(a[w], s) & hm;
    }
    if (valid) {
        #pragma unroll
        for (int w = 0; w <= P; ++w) A[t * AP + w] = a[w];
    }
}

__global__ __launch_bounds__(1024) void bfs_closure(
    const u64* __restrict__ BT_g, u64* __restrict__ A_g, const u32* __restrict__ meta_g)
{
    extern __shared__ u64 sm[];
    u64* A   = sm;                    // KMAX*AP  (71680 B)
    u64* BTL = A + KMAX * AP;         // KMAX*BTP (56320 B)

    const int tid  = threadIdx.x;
    const int lane = tid & 63;
    const int wid  = tid >> 6;
    const int tail = (int)meta_g[0];
    const int nb   = (tail + 63) >> 6;

    for (int r = tid; r < tail; r += 1024) {
        const u64* src = BT_g + (size_t)r * KW;
        u64* dst = BTL + (size_t)r * BTP;
        #pragma unroll
        for (int w = 0; w < KW; ++w) dst[w] = src[w];
    }
    for (int r = tid; r < tail; r += 1024) {
        u64* dst = A + (size_t)r * AP;
        #pragma unroll
        for (int w = 0; w < AP; ++w) dst[w] = 0ull;
        dst[r >> 6] = 1ull << (r & 63);
    }
    __syncthreads();

    auto diag_dispatch = [&](int p) {
        switch (p) {
            case 0: diag_t<0>(A, BTL, 0,       lane, tail); break;
            case 1: diag_t<1>(A, BTL, 64,      lane, tail); break;
            case 2: diag_t<2>(A, BTL, 128,     lane, tail); break;
            case 3: diag_t<3>(A, BTL, 192,     lane, tail); break;
            case 4: diag_t<4>(A, BTL, 256,     lane, tail); break;
            case 5: diag_t<5>(A, BTL, 320,     lane, tail); break;
            case 6: diag_t<6>(A, BTL, 384,     lane, tail); break;
            case 7: diag_t<7>(A, BTL, 448,     lane, tail); break;
            case 8: diag_t<8>(A, BTL, 512,     lane, tail); break;
            default: diag_t<9>(A, BTL, 576,    lane, tail); break;
        }
    };

    // near(p): sources block p-1 -> targets block p; dense readlane, word wid per wave
    auto near_cross = [&](int p) {
        if (wid >= p) return;
        const int sb0 = (p - 1) << 6;
        const int t = (p << 6) + lane;
        u64 av = A[(size_t)(sb0 + lane) * AP + wid];   // source row = lane, word wid
        u64 x = (t < tail) ? BTL[(size_t)t * BTP + (p - 1)] : 0ull;
        u64 acc = 0;
        #pragma unroll 64
        for (int s = 0; s < 64; ++s) {
            u64 hm = ((x >> s) & 1ull) ? ~0ull : 0ull;
            acc |= rdl64(av, s) & hm;
        }
        if (t < tail && acc) A[(size_t)t * AP + wid] |= acc;
    };

    // far(p): sources block p-1 -> target blocks p+1..nb-1; sparse b128 gathers
    auto far_cross = [&](int p) {
        const int sb0 = (p - 1) << 6;
        const int nbf = nb - 1 - p;
        if (nbf <= 0) return;
        const int W2 = (p + 1) >> 1;           // b128 slots covering words 0..p-1
        const int h0 = (W2 + 1) >> 1;
        for (int idx = wid - 1; idx < 2 * nbf; idx += 15) {
            const int tb = p + 1 + (idx >> 1);
            const int half = idx & 1;
            const int s0 = half ? h0 : 0;
            const int s1 = half ? W2 : h0;
            if (s0 >= s1) continue;
            const int t = (tb << 6) + lane;
            u64 x = (t < tail) ? BTL[(size_t)t * BTP + (p - 1)] : 0ull;
            if (!x) continue;
            ulonglong2 acc[5];
            #pragma unroll
            for (int k = 0; k < 5; ++k) { acc[k].x = 0ull; acc[k].y = 0ull; }
            u64 m = x;
            while (m) {
                int s = __ffsll((long long)m) - 1; m &= m - 1;
                const ulonglong2* Ar = (const ulonglong2*)(A + (size_t)(sb0 + s) * AP);
                #pragma unroll
                for (int k = 0; k < 5; ++k)
                    if (k >= s0 && k < s1) { ulonglong2 v = Ar[k]; acc[k].x |= v.x; acc[k].y |= v.y; }
            }
            ulonglong2* At = (ulonglong2*)(A + (size_t)t * AP);
            #pragma unroll
            for (int k = 0; k < 5; ++k)
                if (k >= s0 && k < s1) { ulonglong2 v = At[k]; v.x |= acc[k].x; v.y |= acc[k].y; At[k] = v; }
        }
    };

    if (nb > 0) {
        if (wid == 0) {
            __builtin_amdgcn_s_setprio(1); diag_dispatch(0); __builtin_amdgcn_s_setprio(0);
        }
        __syncthreads();
        for (int p = 1; p < nb; ++p) {
            near_cross(p);
            __syncthreads();
            if (wid == 0) {
                __builtin_amdgcn_s_setprio(1); diag_dispatch(p); __builtin_amdgcn_s_setprio(0);
            } else {
                far_cross(p);
            }
            __syncthreads();
        }
    }
    __syncthreads();
    for (int r = tid; r < tail; r += 1024) {
        const u64* src = A + (size_t)r * AP;
        u64* dst = A_g + (size_t)r * KW;
        #pragma unroll
        for (int w = 0; w < KW; ++w) dst[w] = src[w];
    }
}

// ---- K5: expand to f32 output (dag = E & masks & ~A) ----
__global__ __launch_bounds__(256) void final_expand(
    const u32* __restrict__ E, const u64* __restrict__ A_g,
    const u16* __restrict__ posof_g, const u32* __restrict__ meta_g,
    float4* __restrict__ out)
{
    int gid = blockIdx.x * 256 + threadIdx.x;
    int i = gid >> 8;
    int j0 = (gid & 255) << 2;
    u32 tail = meta_g[0];
    u32 pi = posof_g[i];
    float r[4] = {0.f, 0.f, 0.f, 0.f};
    if (pi == 0xFFFFu) {                              // root row: E & ~root
        u32 wv = E[(size_t)i * NW + (j0 >> 5)];
        #pragma unroll
        for (int t = 0; t < 4; ++t) {
            u32 pj = posof_g[j0 + t];
            bool nz = ((wv >> ((j0 & 31) + t)) & 1u) && (pj != 0xFFFFu);
            r[t] = nz ? 1.0f : 0.0f;
        }
    } else if (pi < tail) {                           // processed nonroot row
        const u64* Arow = A_g + (size_t)pi * KW;
        u32 wv = E[(size_t)i * NW + (j0 >> 5)];
        #pragma unroll
        for (int t = 0; t < 4; ++t) {
            u32 pj = posof_g[j0 + t];
            bool eb = (wv >> ((j0 & 31) + t)) & 1u;
            if (eb && pj != 0xFFFFu) {
                u64 ab = (pj < (u32)KMAX) ? Arow[pj >> 6] : 0ull;
                r[t] = ((ab >> (pj & 63)) & 1ull) ? 0.0f : 1.0f;
            }
        }
    }
    out[gid] = make_float4(r[0], r[1], r[2], r[3]);
}

extern "C" void kernel_launch(void* const* d_in, const int* in_sizes, int n_in,
                              void* d_out, int out_size, void* d_ws, size_t ws_size,
                              hipStream_t stream) {
    const float* root_probs = (const float*)d_in[0];
    const float* edge_probs = (const float*)d_in[1];
    const float* g_roots    = (const float*)d_in[2];
    const float* g_edges    = (const float*)d_in[3];

    char* ws = (char*)d_ws;
    u32* E       = (u32*)(ws);                 // 131072 B
    u64* BT_g    = (u64*)(ws + 131072);        // 51200 B
    u64* A_g     = (u64*)(ws + 182272);        // 51200 B
    u16* posof_g = (u16*)(ws + 233472);        // 2048 B
    u16* npl_g   = (u16*)(ws + 235520);        // 1280 B
    u32* meta_g  = (u32*)(ws + 236800);        // 64 B

    edge_bits_kernel<<<NN * NN / 256, 256, 0, stream>>>(edge_probs, g_edges, E);

    size_t lds_seed = (size_t)(16 * NBIN + NBIN + 64) * 4;   // 69888 B
    hipFuncSetAttribute((const void*)seed_kernel,
                        hipFuncAttributeMaxDynamicSharedMemorySize, (int)lds_seed);
    seed_kernel<<<1, NN, lds_seed, stream>>>(root_probs, g_roots, E, meta_g, posof_g, npl_g);

    transposeB_kernel<<<(KMAX * KW + 255) / 256, 256, 0, stream>>>(E, npl_g, meta_g, BT_g);

    size_t lds = (size_t)KMAX * AP * 8 + (size_t)KMAX * BTP * 8;   // 128000 B
    hipFuncSetAttribute((const void*)bfs_closure,
                        hipFuncAttributeMaxDynamicSharedMemorySize, (int)lds);
    bfs_closure<<<1, NN, lds, stream>>>(BT_g, A_g, meta_g);

    final_expand<<<NN * NN / 4 / 256, 256, 0, stream>>>(E, A_g, posof_g, meta_g,
                                                        (float4*)d_out);
}

// Round 16
// 120.226 us; speedup vs baseline: 2.2516x; 1.0828x over previous
//
#include <hip/hip_runtime.h>

#define NN 1024
#define NW 32            // u32 words per full 1024-bit row
#define KMAX 640         // max #non-roots (P(K>640) < 1e-14)
#define KW 10            // u64 words per compact row
#define AP  14           // A LDS row stride (u64): 112 B, 16-aligned for b128
#define BTP 11           // BT LDS row stride (u64)
#define NBIN 1024

typedef unsigned int u32;
typedef unsigned long long u64;
typedef unsigned short u16;

__device__ __forceinline__ u64 rdl64(u64 v, int s) {   // broadcast lane s (uniform s)
    u32 lo = (u32)__builtin_amdgcn_readlane((int)(u32)v, s);
    u32 hi = (u32)__builtin_amdgcn_readlane((int)(u32)(v >> 32), s);
    return ((u64)hi << 32) | (u64)lo;
}

// ---- K1: edge hard bits -> E ----
__global__ void edge_bits_kernel(const float* __restrict__ ep, const float* __restrict__ ge,
                                 u32* __restrict__ E)
{
    int idx = blockIdx.x * blockDim.x + threadIdx.x;
    float p = ep[idx];
    float2 g = reinterpret_cast<const float2*>(ge)[idx];
    bool hard = (p + g.x) > ((1.0f - p) + g.y);
    u64 m = __ballot(hard);
    int lane = threadIdx.x & 63;
    if ((lane & 31) == 0) E[idx >> 5] = (u32)(m >> (lane & 32));
}

// ---- K2: roots + seed; histogram counting sort (stable by (rank, tid)) ----
__global__ __launch_bounds__(1024) void seed_kernel(
    const float* __restrict__ rp, const float* __restrict__ gr,
    const u32* __restrict__ Eg, u32* __restrict__ meta_g,
    u16* __restrict__ posof_g, u16* __restrict__ npl_g)
{
    extern __shared__ u32 sd[];
    u32* hist    = sd;                    // 16 * NBIN
    u32* scan    = hist + 16 * NBIN;      // NBIN
    u32* rootm   = scan + NBIN;           // 32
    u32* rootpre = rootm + 32;            // 32

    const int tid = threadIdx.x;
    const int lane = tid & 63;
    const int wid  = tid >> 6;

    float p0 = rp[tid];
    float2 g0 = reinterpret_cast<const float2*>(gr)[tid];
    bool isroot = (p0 + g0.x) > ((1.0f - p0) + g0.y);
    u64 rm = __ballot(isroot);
    if (lane == 0) { rootm[wid * 2] = (u32)rm; rootm[wid * 2 + 1] = (u32)(rm >> 32); }
    for (int i = tid; i < 16 * NBIN; i += 1024) hist[i] = 0u;
    __syncthreads();
    if (tid == 0) {
        u32 s = 0;
        #pragma unroll
        for (int w = 0; w < 32; ++w) { rootpre[w] = s; s += __popc(rootm[w]); }
    }
    __syncthreads();

    int fr = -1;
    if (!isroot) {
        int rrank = 0;
        for (int i2 = 0; i2 < NN; ++i2) {
            if ((rootm[i2 >> 5] >> (i2 & 31)) & 1u) {
                u32 wv = Eg[(size_t)i2 * NW + (tid >> 5)];
                if (fr < 0 && ((wv >> (tid & 31)) & 1u)) fr = rrank;
                ++rrank;
                if (__all(fr >= 0)) break;
            }
        }
    }
    bool found = (!isroot) && (fr >= 0);
    u32 ridx = found ? (u32)fr : 0xFFFFFFFFu;

    if (found) atomicAdd(&hist[wid * NBIN + ridx], 1u);
    __syncthreads();

    for (int r = tid; r < NBIN; r += 1024) {
        u32 s = 0;
        #pragma unroll
        for (int w = 0; w < 16; ++w) s += hist[w * NBIN + r];
        scan[r] = s;
    }
    __syncthreads();
    for (int off = 1; off < NBIN; off <<= 1) {
        u32 v = 0;
        if (tid < NBIN && tid >= off) v = scan[tid - off];
        __syncthreads();
        if (tid < NBIN) scan[tid] += v;
        __syncthreads();
    }

    int intra = 0;
    #pragma unroll 64
    for (int l2 = 0; l2 < 64; ++l2) {
        u32 rr = (u32)__builtin_amdgcn_readlane((int)ridx, l2);
        intra += (rr == ridx && l2 < lane) ? 1 : 0;
    }
    u32 pos = 0;
    if (found) {
        u32 base = (ridx > 0) ? scan[ridx - 1] : 0u;
        u32 wb = 0;
        for (int w = 0; w < wid; ++w) wb += hist[w * NBIN + ridx];
        pos = base + wb + (u32)intra;
        if (pos < KMAX) npl_g[pos] = (u16)tid;
    }
    posof_g[tid] = isroot ? (u16)0xFFFF : (found ? (u16)pos : (u16)1023);
    if (tid == 0) {
        u32 tl = scan[NBIN - 1];
        meta_g[0] = (tl < (u32)KMAX) ? tl : (u32)KMAX;
    }
}

// ---- K3: BT[t][w'] bit s = E[node(w'*64+s)][node(t)] ----
__global__ __launch_bounds__(256) void transposeB_kernel(
    const u32* __restrict__ E, const u16* __restrict__ npl_g,
    const u32* __restrict__ meta_g, u64* __restrict__ BT_g)
{
    __shared__ u16 npL[KMAX];
    const int tid = threadIdx.x;
    for (int k = tid; k < KMAX; k += 256) npL[k] = npl_g[k];
    u32 tail = meta_g[0];
    __syncthreads();
    int gid = blockIdx.x * 256 + tid;        // t*KW + w
    int t = gid / KW, w = gid - t * KW;
    if (t >= (int)tail) return;
    int jt = npL[t];
    u64 acc = 0;
    int cb = w * 64;
    for (int b = 0; b < 64; ++b) {
        int s = cb + b;
        if (s < (int)tail) {
            int is = npL[s];
            acc |= ((u64)((E[(size_t)is * NW + (jt >> 5)] >> (jt & 31)) & 1u)) << b;
        }
    }
    BT_g[gid] = acc;
}

// ---- K4: upper-triangular transitive closure; per-WORD parallel diag ----
__global__ __launch_bounds__(1024) void bfs_closure(
    const u64* __restrict__ BT_g, u64* __restrict__ A_g, const u32* __restrict__ meta_g)
{
    extern __shared__ u64 sm[];
    u64* A   = sm;                    // KMAX*AP  (71680 B)
    u64* BTL = A + KMAX * AP;         // KMAX*BTP (56320 B)

    const int tid  = threadIdx.x;
    const int lane = tid & 63;
    const int wid  = tid >> 6;
    const int tail = (int)meta_g[0];
    const int nb   = (tail + 63) >> 6;

    for (int r = tid; r < tail; r += 1024) {
        const u64* src = BT_g + (size_t)r * KW;
        u64* dst = BTL + (size_t)r * BTP;
        #pragma unroll
        for (int w = 0; w < KW; ++w) dst[w] = src[w];
    }
    for (int r = tid; r < tail; r += 1024) {
        u64* dst = A + (size_t)r * AP;
        #pragma unroll
        for (int w = 0; w < AP; ++w) dst[w] = 0ull;
        dst[r >> 6] = 1ull << (r & 63);
    }
    __syncthreads();

    for (int p = 0; p < nb; ++p) {
        if (wid <= p && wid < KW) {
            // ---- near(block p-1 -> block p) + diag(block p), word wid, one wave ----
            __builtin_amdgcn_s_setprio(1);
            const int t = (p << 6) + lane;
            const bool valid = t < tail;
            u64 av = valid ? A[(size_t)t * AP + wid] : 0ull;
            if (wid < p) {
                // block p-1 is always full (only last block partial, never a source)
                u64 asrc = A[(size_t)(((p - 1) << 6) + lane) * AP + wid];
                u64 xb = valid ? BTL[(size_t)t * BTP + (p - 1)] : 0ull;
                #pragma unroll 64
                for (int s = 0; s < 64; ++s) {
                    u64 hm = ((xb >> s) & 1ull) ? ~0ull : 0ull;
                    av |= rdl64(asrc, s) & hm;
                }
            }
            u64 xd = valid ? BTL[(size_t)t * BTP + p] : 0ull;
            xd &= (1ull << lane) - 1ull;              // only sources s < lane
            #pragma unroll 63
            for (int s = 0; s < 63; ++s) {
                u64 hm = ((xd >> s) & 1ull) ? ~0ull : 0ull;
                av |= rdl64(av, s) & hm;
            }
            if (valid) A[(size_t)t * AP + wid] = av;
            __builtin_amdgcn_s_setprio(0);
        } else if (p >= 1 && wid > p) {
            // ---- far: sources block p-1 -> target blocks p+1..nb-1 (sparse b128) ----
            const int sb0 = (p - 1) << 6;
            const int nbf = nb - 1 - p;
            if (nbf > 0) {
                const int W2 = (p + 1) >> 1;          // b128 slots covering words 0..p-1
                const int h0 = (W2 + 1) >> 1;
                const int nworkers = 15 - p;
                for (int idx = wid - p - 1; idx < 2 * nbf; idx += nworkers) {
                    const int tb = p + 1 + (idx >> 1);
                    const int half = idx & 1;
                    const int s0 = half ? h0 : 0;
                    const int s1 = half ? W2 : h0;
                    if (s0 >= s1) continue;
                    const int t = (tb << 6) + lane;
                    u64 x = (t < tail) ? BTL[(size_t)t * BTP + (p - 1)] : 0ull;
                    if (!x) continue;
                    ulonglong2 acc[5];
                    #pragma unroll
                    for (int k = 0; k < 5; ++k) { acc[k].x = 0ull; acc[k].y = 0ull; }
                    u64 m = x;
                    while (m) {
                        int s = __ffsll((long long)m) - 1; m &= m - 1;
                        const ulonglong2* Ar = (const ulonglong2*)(A + (size_t)(sb0 + s) * AP);
                        #pragma unroll
                        for (int k = 0; k < 5; ++k)
                            if (k >= s0 && k < s1) { ulonglong2 v = Ar[k]; acc[k].x |= v.x; acc[k].y |= v.y; }
                    }
                    ulonglong2* At = (ulonglong2*)(A + (size_t)t * AP);
                    #pragma unroll
                    for (int k = 0; k < 5; ++k)
                        if (k >= s0 && k < s1) { ulonglong2 v = At[k]; v.x |= acc[k].x; v.y |= acc[k].y; At[k] = v; }
                }
            }
        }
        __syncthreads();                               // one barrier per phase
    }

    for (int r = tid; r < tail; r += 1024) {
        const u64* src = A + (size_t)r * AP;
        u64* dst = A_g + (size_t)r * KW;
        #pragma unroll
        for (int w = 0; w < KW; ++w) dst[w] = src[w];
    }
}

// ---- K5: expand to f32 output (dag = E & masks & ~A) ----
__global__ __launch_bounds__(256) void final_expand(
    const u32* __restrict__ E, const u64* __restrict__ A_g,
    const u16* __restrict__ posof_g, const u32* __restrict__ meta_g,
    float4* __restrict__ out)
{
    int gid = blockIdx.x * 256 + threadIdx.x;
    int i = gid >> 8;
    int j0 = (gid & 255) << 2;
    u32 tail = meta_g[0];
    u32 pi = posof_g[i];
    float r[4] = {0.f, 0.f, 0.f, 0.f};
    if (pi == 0xFFFFu) {                              // root row: E & ~root
        u32 wv = E[(size_t)i * NW + (j0 >> 5)];
        #pragma unroll
        for (int t = 0; t < 4; ++t) {
            u32 pj = posof_g[j0 + t];
            bool nz = ((wv >> ((j0 & 31) + t)) & 1u) && (pj != 0xFFFFu);
            r[t] = nz ? 1.0f : 0.0f;
        }
    } else if (pi < tail) {                           // processed nonroot row
        const u64* Arow = A_g + (size_t)pi * KW;
        u32 wv = E[(size_t)i * NW + (j0 >> 5)];
        #pragma unroll
        for (int t = 0; t < 4; ++t) {
            u32 pj = posof_g[j0 + t];
            bool eb = (wv >> ((j0 & 31) + t)) & 1u;
            if (eb && pj != 0xFFFFu) {
                u64 ab = (pj < (u32)KMAX) ? Arow[pj >> 6] : 0ull;
                r[t] = ((ab >> (pj & 63)) & 1ull) ? 0.0f : 1.0f;
            }
        }
    }
    out[gid] = make_float4(r[0], r[1], r[2], r[3]);
}

extern "C" void kernel_launch(void* const* d_in, const int* in_sizes, int n_in,
                              void* d_out, int out_size, void* d_ws, size_t ws_size,
                              hipStream_t stream) {
    const float* root_probs = (const float*)d_in[0];
    const float* edge_probs = (const float*)d_in[1];
    const float* g_roots    = (const float*)d_in[2];
    const float* g_edges    = (const float*)d_in[3];

    char* ws = (char*)d_ws;
    u32* E       = (u32*)(ws);                 // 131072 B
    u64* BT_g    = (u64*)(ws + 131072);        // 51200 B
    u64* A_g     = (u64*)(ws + 182272);        // 51200 B
    u16* posof_g = (u16*)(ws + 233472);        // 2048 B
    u16* npl_g   = (u16*)(ws + 235520);        // 1280 B
    u32* meta_g  = (u32*)(ws + 236800);        // 64 B

    edge_bits_kernel<<<NN * NN / 256, 256, 0, stream>>>(edge_probs, g_edges, E);

    size_t lds_seed = (size_t)(16 * NBIN + NBIN + 64) * 4;   // 69888 B
    hipFuncSetAttribute((const void*)seed_kernel,
                        hipFuncAttributeMaxDynamicSharedMemorySize, (int)lds_seed);
    seed_kernel<<<1, NN, lds_seed, stream>>>(root_probs, g_roots, E, meta_g, posof_g, npl_g);

    transposeB_kernel<<<(KMAX * KW + 255) / 256, 256, 0, stream>>>(E, npl_g, meta_g, BT_g);

    size_t lds = (size_t)KMAX * AP * 8 + (size_t)KMAX * BTP * 8;   // 128000 B
    hipFuncSetAttribute((const void*)bfs_closure,
                        hipFuncAttributeMaxDynamicSharedMemorySize, (int)lds);
    bfs_closure<<<1, NN, lds, stream>>>(BT_g, A_g, meta_g);

    final_expand<<<NN * NN / 4 / 256, 256, 0, stream>>>(E, A_g, posof_g, meta_g,
                                                        (float4*)d_out);
}

// Round 17
// 96.534 us; speedup vs baseline: 2.8043x; 1.2454x over previous
//
#include <hip/hip_runtime.h>

#define NN 1024
#define NW 32            // u32 words per full 1024-bit row
#define KMAX 640         // max #non-roots (P(K>640) < 1e-14)
#define KW 10            // u64 words per compact row
#define AP  13           // A LDS row stride (u64), odd -> bank spread
#define BTP 11           // BT LDS row stride (u64), odd -> bank spread
#define NBIN 1024

typedef unsigned int u32;
typedef unsigned long long u64;
typedef unsigned short u16;

__device__ __forceinline__ u64 rdl64(u64 v, int s) {   // broadcast lane s (uniform s)
    u32 lo = (u32)__builtin_amdgcn_readlane((int)(u32)v, s);
    u32 hi = (u32)__builtin_amdgcn_readlane((int)(u32)(v >> 32), s);
    return ((u64)hi << 32) | (u64)lo;
}
__device__ __forceinline__ u64 bitmask64(u64 x, int s) {   // all-ones if bit s of x
    return (u64)(((long long)(x << (63 - s))) >> 63);
}

// ---- K1: edge hard bits -> E ----
__global__ void edge_bits_kernel(const float* __restrict__ ep, const float* __restrict__ ge,
                                 u32* __restrict__ E)
{
    int idx = blockIdx.x * blockDim.x + threadIdx.x;
    float p = ep[idx];
    float2 g = reinterpret_cast<const float2*>(ge)[idx];
    bool hard = (p + g.x) > ((1.0f - p) + g.y);
    u64 m = __ballot(hard);
    int lane = threadIdx.x & 63;
    if ((lane & 31) == 0) E[idx >> 5] = (u32)(m >> (lane & 32));
}

// ---- K2: roots + seed; histogram counting sort, wave-hierarchical scan ----
__global__ __launch_bounds__(1024) void seed_kernel(
    const float* __restrict__ rp, const float* __restrict__ gr,
    const u32* __restrict__ Eg, u32* __restrict__ meta_g,
    u16* __restrict__ posof_g, u16* __restrict__ npl_g)
{
    extern __shared__ u32 sd[];
    u32* hist  = sd;                    // NBIN*16, layout [bin*16 + wave]
    u32* scan  = hist + NBIN * 16;      // NBIN (inclusive scan of totals)
    u32* wtot  = scan + NBIN;           // 16
    u32* rootm = wtot + 16;             // 32

    const int tid = threadIdx.x;
    const int lane = tid & 63;
    const int wid  = tid >> 6;

    float p0 = rp[tid];
    float2 g0 = reinterpret_cast<const float2*>(gr)[tid];
    bool isroot = (p0 + g0.x) > ((1.0f - p0) + g0.y);
    u64 rm = __ballot(isroot);
    if (lane == 0) { rootm[wid * 2] = (u32)rm; rootm[wid * 2 + 1] = (u32)(rm >> 32); }
    for (int i = tid; i < NBIN * 16; i += 1024) hist[i] = 0u;
    __syncthreads();

    // rank of first root hitting node tid (scan root rows of E)
    int fr = -1;
    if (!isroot) {
        int rrank = 0;
        for (int i2 = 0; i2 < NN; ++i2) {
            if ((rootm[i2 >> 5] >> (i2 & 31)) & 1u) {
                u32 wv = Eg[(size_t)i2 * NW + (tid >> 5)];
                if (fr < 0 && ((wv >> (tid & 31)) & 1u)) fr = rrank;
                ++rrank;
                if (__all(fr >= 0)) break;
            }
        }
    }
    bool found = (!isroot) && (fr >= 0);
    u32 ridx = found ? (u32)fr : 0xFFFFFFFFu;

    if (found) atomicAdd(&hist[ridx * 16 + wid], 1u);
    __syncthreads();

    // per-bin totals (consecutive 16 words) + wave-hierarchical inclusive scan
    u32 v;
    {
        const uint4* h4 = (const uint4*)(hist + tid * 16);
        uint4 a = h4[0], b = h4[1], c = h4[2], d = h4[3];
        v = a.x + a.y + a.z + a.w + b.x + b.y + b.z + b.w
          + c.x + c.y + c.z + c.w + d.x + d.y + d.z + d.w;
    }
    #pragma unroll
    for (int d2 = 1; d2 < 64; d2 <<= 1) {
        u32 u = (u32)__shfl_up((int)v, d2);
        if (lane >= d2) v += u;
    }
    if (lane == 63) wtot[wid] = v;
    __syncthreads();
    {
        u32 off = 0;
        #pragma unroll
        for (int w2 = 0; w2 < 16; ++w2) off += (w2 < wid) ? wtot[w2] : 0u;
        v += off;
        scan[tid] = v;
    }
    __syncthreads();

    // stable intra-wave index among equal ranks
    int intra = 0;
    #pragma unroll 64
    for (int l2 = 0; l2 < 64; ++l2) {
        u32 rr = (u32)__builtin_amdgcn_readlane((int)ridx, l2);
        intra += (rr == ridx && l2 < lane) ? 1 : 0;
    }
    u32 pos = 0;
    if (found) {
        u32 base = (ridx > 0) ? scan[ridx - 1] : 0u;
        u32 wb = 0;
        for (int w = 0; w < wid; ++w) wb += hist[ridx * 16 + w];
        pos = base + wb + (u32)intra;
        if (pos < KMAX) npl_g[pos] = (u16)tid;
    }
    posof_g[tid] = isroot ? (u16)0xFFFF : (found ? (u16)pos : (u16)1023);
    if (tid == 0) {
        u32 tl = scan[NBIN - 1];
        meta_g[0] = (tl < (u32)KMAX) ? tl : (u32)KMAX;
    }
}

// ---- K3: BT[t][w'] bit s = E[node(w'*64+s)][node(t)] ----
__global__ __launch_bounds__(256) void transposeB_kernel(
    const u32* __restrict__ E, const u16* __restrict__ npl_g,
    const u32* __restrict__ meta_g, u64* __restrict__ BT_g)
{
    __shared__ u16 npL[KMAX];
    const int tid = threadIdx.x;
    for (int k = tid; k < KMAX; k += 256) npL[k] = npl_g[k];
    u32 tail = meta_g[0];
    __syncthreads();
    int gid = blockIdx.x * 256 + tid;        // t*KW + w
    int t = gid / KW, w = gid - t * KW;
    if (t >= (int)tail) return;
    int jt = npL[t];
    u64 acc = 0;
    int cb = w * 64;
    for (int b = 0; b < 64; ++b) {
        int s = cb + b;
        if (s < (int)tail) {
            int is = npL[s];
            acc |= ((u64)((E[(size_t)is * NW + (jt >> 5)] >> (jt & 31)) & 1u)) << b;
        }
    }
    BT_g[gid] = acc;
}

// ---- K4: upper-triangular transitive closure; ALL-dense readlane chains ----
__global__ __launch_bounds__(1024) void bfs_closure(
    const u64* __restrict__ BT_g, u64* __restrict__ A_g, const u32* __restrict__ meta_g)
{
    extern __shared__ u64 sm[];
    u64* A   = sm;                    // KMAX*AP  (66560 B)
    u64* BTL = A + KMAX * AP;         // KMAX*BTP (56320 B)

    const int tid  = threadIdx.x;
    const int lane = tid & 63;
    const int wid  = tid >> 6;
    const int tail = (int)meta_g[0];
    const int nb   = (tail + 63) >> 6;

    for (int r = tid; r < tail; r += 1024) {
        const u64* src = BT_g + (size_t)r * KW;
        u64* dst = BTL + (size_t)r * BTP;
        #pragma unroll
        for (int w = 0; w < KW; ++w) dst[w] = src[w];
    }
    for (int r = tid; r < tail; r += 1024) {
        u64* dst = A + (size_t)r * AP;
        #pragma unroll
        for (int w = 0; w < AP; ++w) dst[w] = (w == (r >> 6)) ? (1ull << (r & 63)) : 0ull;
    }
    __syncthreads();

    for (int p = 0; p < nb; ++p) {
        if (wid <= p) {
            // ---- near(block p-1 -> block p) + diag(block p), word wid ----
            __builtin_amdgcn_s_setprio(1);
            const int t = (p << 6) + lane;
            const bool valid = t < tail;
            u64 av = valid ? A[(size_t)t * AP + wid] : 0ull;
            if (wid < p) {
                u64 asrc = A[(size_t)(((p - 1) << 6) + lane) * AP + wid];
                u64 xb = valid ? BTL[(size_t)t * BTP + (p - 1)] : 0ull;
                #pragma unroll 64
                for (int s = 0; s < 64; ++s)
                    av |= rdl64(asrc, s) & bitmask64(xb, s);
            }
            u64 xd = valid ? BTL[(size_t)t * BTP + p] : 0ull;
            xd &= (1ull << lane) - 1ull;              // only sources s < lane
            #pragma unroll 63
            for (int s = 0; s < 63; ++s)
                av |= rdl64(av, s) & bitmask64(xd, s);
            if (valid) A[(size_t)t * AP + wid] = av;
            __builtin_amdgcn_s_setprio(0);
        } else if (p >= 1) {
            // ---- far: dense chains, one (target-block, word) per chain ----
            const int nbf = nb - 1 - p;
            const int C = p * nbf;
            const int nworkers = 15 - p;
            const int sb0 = (p - 1) << 6;
            for (int c = wid - p - 1; c < C; c += nworkers) {
                const int q = c / p;
                const int w = c - q * p;
                const int t = ((p + 1 + q) << 6) + lane;
                const bool valid = t < tail;
                u64 asrc = A[(size_t)(sb0 + lane) * AP + w];
                u64 x  = valid ? BTL[(size_t)t * BTP + (p - 1)] : 0ull;
                u64 av = valid ? A[(size_t)t * AP + w] : 0ull;
                #pragma unroll 64
                for (int s = 0; s < 64; ++s)
                    av |= rdl64(asrc, s) & bitmask64(x, s);
                if (valid) A[(size_t)t * AP + w] = av;
            }
        }
        __syncthreads();                               // one barrier per phase
    }

    for (int r = tid; r < tail; r += 1024) {
        const u64* src = A + (size_t)r * AP;
        u64* dst = A_g + (size_t)r * KW;
        #pragma unroll
        for (int w = 0; w < KW; ++w) dst[w] = src[w];
    }
}

// ---- K5: expand to f32 output (dag = E & masks & ~A) ----
__global__ __launch_bounds__(256) void final_expand(
    const u32* __restrict__ E, const u64* __restrict__ A_g,
    const u16* __restrict__ posof_g, const u32* __restrict__ meta_g,
    float4* __restrict__ out)
{
    int gid = blockIdx.x * 256 + threadIdx.x;
    int i = gid >> 8;
    int j0 = (gid & 255) << 2;
    u32 tail = meta_g[0];
    u32 pi = posof_g[i];
    float r[4] = {0.f, 0.f, 0.f, 0.f};
    if (pi == 0xFFFFu) {                              // root row: E & ~root
        u32 wv = E[(size_t)i * NW + (j0 >> 5)];
        #pragma unroll
        for (int t = 0; t < 4; ++t) {
            u32 pj = posof_g[j0 + t];
            bool nz = ((wv >> ((j0 & 31) + t)) & 1u) && (pj != 0xFFFFu);
            r[t] = nz ? 1.0f : 0.0f;
        }
    } else if (pi < tail) {                           // processed nonroot row
        const u64* Arow = A_g + (size_t)pi * KW;
        u32 wv = E[(size_t)i * NW + (j0 >> 5)];
        #pragma unroll
        for (int t = 0; t < 4; ++t) {
            u32 pj = posof_g[j0 + t];
            bool eb = (wv >> ((j0 & 31) + t)) & 1u;
            if (eb && pj != 0xFFFFu) {
                u64 ab = (pj < (u32)KMAX) ? Arow[pj >> 6] : 0ull;
                r[t] = ((ab >> (pj & 63)) & 1ull) ? 0.0f : 1.0f;
            }
        }
    }
    out[gid] = make_float4(r[0], r[1], r[2], r[3]);
}

extern "C" void kernel_launch(void* const* d_in, const int* in_sizes, int n_in,
                              void* d_out, int out_size, void* d_ws, size_t ws_size,
                              hipStream_t stream) {
    const float* root_probs = (const float*)d_in[0];
    const float* edge_probs = (const float*)d_in[1];
    const float* g_roots    = (const float*)d_in[2];
    const float* g_edges    = (const float*)d_in[3];

    char* ws = (char*)d_ws;
    u32* E       = (u32*)(ws);                 // 131072 B
    u64* BT_g    = (u64*)(ws + 131072);        // 51200 B
    u64* A_g     = (u64*)(ws + 182272);        // 51200 B
    u16* posof_g = (u16*)(ws + 233472);        // 2048 B
    u16* npl_g   = (u16*)(ws + 235520);        // 1280 B
    u32* meta_g  = (u32*)(ws + 236800);        // 64 B

    edge_bits_kernel<<<NN * NN / 256, 256, 0, stream>>>(edge_probs, g_edges, E);

    size_t lds_seed = (size_t)(NBIN * 16 + NBIN + 16 + 32) * 4;   // 69824 B
    hipFuncSetAttribute((const void*)seed_kernel,
                        hipFuncAttributeMaxDynamicSharedMemorySize, (int)lds_seed);
    seed_kernel<<<1, NN, lds_seed, stream>>>(root_probs, g_roots, E, meta_g, posof_g, npl_g);

    transposeB_kernel<<<(KMAX * KW + 255) / 256, 256, 0, stream>>>(E, npl_g, meta_g, BT_g);

    size_t lds = (size_t)KMAX * AP * 8 + (size_t)KMAX * BTP * 8;   // 122880 B
    hipFuncSetAttribute((const void*)bfs_closure,
                        hipFuncAttributeMaxDynamicSharedMemorySize, (int)lds);
    bfs_closure<<<1, NN, lds, stream>>>(BT_g, A_g, meta_g);

    final_expand<<<NN * NN / 4 / 256, 256, 0, stream>>>(E, A_g, posof_g, meta_g,
                                                        (float4*)d_out);
}

// Round 18
// 62.929 us; speedup vs baseline: 4.3018x; 1.5340x over previous
//
#include <hip/hip_runtime.h>

#define NN 1024
#define NW 32            // u32 words per full 1024-bit row
#define KMAX 640         // max #non-roots (P(K>640) < 1e-14)
#define KW 10            // u64 words per compact row
#define AP  13           // A LDS row stride (u64), odd -> bank spread
#define BTP 11           // BT LDS row stride (u64), odd -> bank spread
#define NBIN 1024

typedef unsigned int u32;
typedef unsigned long long u64;
typedef unsigned short u16;

__device__ __forceinline__ u64 rdl64(u64 v, int s) {   // broadcast lane s (uniform s)
    u32 lo = (u32)__builtin_amdgcn_readlane((int)(u32)v, s);
    u32 hi = (u32)__builtin_amdgcn_readlane((int)(u32)(v >> 32), s);
    return ((u64)hi << 32) | (u64)lo;
}
__device__ __forceinline__ u64 bitmask64(u64 x, int s) {   // all-ones if bit s of x
    return (u64)(((long long)(x << (63 - s))) >> 63);
}

// ---- K1: edge hard bits -> E ----
__global__ void edge_bits_kernel(const float* __restrict__ ep, const float* __restrict__ ge,
                                 u32* __restrict__ E)
{
    int idx = blockIdx.x * blockDim.x + threadIdx.x;
    float p = ep[idx];
    float2 g = reinterpret_cast<const float2*>(ge)[idx];
    bool hard = (p + g.x) > ((1.0f - p) + g.y);
    u64 m = __ballot(hard);
    int lane = threadIdx.x & 63;
    if ((lane & 31) == 0) E[idx >> 5] = (u32)(m >> (lane & 32));
}

// ---- K2: roots + seed; histogram counting sort, wave-hierarchical scan ----
__global__ __launch_bounds__(1024) void seed_kernel(
    const float* __restrict__ rp, const float* __restrict__ gr,
    const u32* __restrict__ Eg, u32* __restrict__ meta_g,
    u16* __restrict__ posof_g, u16* __restrict__ npl_g)
{
    extern __shared__ u32 sd[];
    u32* hist  = sd;                    // NBIN*16, layout [bin*16 + wave]
    u32* scan  = hist + NBIN * 16;      // NBIN (inclusive scan of totals)
    u32* wtot  = scan + NBIN;           // 16
    u32* rootm = wtot + 16;             // 32

    const int tid = threadIdx.x;
    const int lane = tid & 63;
    const int wid  = tid >> 6;

    float p0 = rp[tid];
    float2 g0 = reinterpret_cast<const float2*>(gr)[tid];
    bool isroot = (p0 + g0.x) > ((1.0f - p0) + g0.y);
    u64 rm = __ballot(isroot);
    if (lane == 0) { rootm[wid * 2] = (u32)rm; rootm[wid * 2 + 1] = (u32)(rm >> 32); }
    for (int i = tid; i < NBIN * 16; i += 1024) hist[i] = 0u;
    __syncthreads();

    int fr = -1;
    if (!isroot) {
        int rrank = 0;
        for (int i2 = 0; i2 < NN; ++i2) {
            if ((rootm[i2 >> 5] >> (i2 & 31)) & 1u) {
                u32 wv = Eg[(size_t)i2 * NW + (tid >> 5)];
                if (fr < 0 && ((wv >> (tid & 31)) & 1u)) fr = rrank;
                ++rrank;
                if (__all(fr >= 0)) break;
            }
        }
    }
    bool found = (!isroot) && (fr >= 0);
    u32 ridx = found ? (u32)fr : 0xFFFFFFFFu;

    if (found) atomicAdd(&hist[ridx * 16 + wid], 1u);
    __syncthreads();

    u32 v;
    {
        const uint4* h4 = (const uint4*)(hist + tid * 16);
        uint4 a = h4[0], b = h4[1], c = h4[2], d = h4[3];
        v = a.x + a.y + a.z + a.w + b.x + b.y + b.z + b.w
          + c.x + c.y + c.z + c.w + d.x + d.y + d.z + d.w;
    }
    #pragma unroll
    for (int d2 = 1; d2 < 64; d2 <<= 1) {
        u32 u = (u32)__shfl_up((int)v, d2);
        if (lane >= d2) v += u;
    }
    if (lane == 63) wtot[wid] = v;
    __syncthreads();
    {
        u32 off = 0;
        #pragma unroll
        for (int w2 = 0; w2 < 16; ++w2) off += (w2 < wid) ? wtot[w2] : 0u;
        v += off;
        scan[tid] = v;
    }
    __syncthreads();

    int intra = 0;
    #pragma unroll 64
    for (int l2 = 0; l2 < 64; ++l2) {
        u32 rr = (u32)__builtin_amdgcn_readlane((int)ridx, l2);
        intra += (rr == ridx && l2 < lane) ? 1 : 0;
    }
    u32 pos = 0;
    if (found) {
        u32 base = (ridx > 0) ? scan[ridx - 1] : 0u;
        u32 wb = 0;
        for (int w = 0; w < wid; ++w) wb += hist[ridx * 16 + w];
        pos = base + wb + (u32)intra;
        if (pos < KMAX) npl_g[pos] = (u16)tid;
    }
    posof_g[tid] = isroot ? (u16)0xFFFF : (found ? (u16)pos : (u16)1023);
    if (tid == 0) {
        u32 tl = scan[NBIN - 1];
        meta_g[0] = (tl < (u32)KMAX) ? tl : (u32)KMAX;
    }
}

// ---- K3: BT via wave ballot — wave handles (t, w); lane s tests E[node(w*64+s)][node(t)] ----
__global__ __launch_bounds__(256) void transposeB_kernel(
    const u32* __restrict__ E, const u16* __restrict__ npl_g,
    const u32* __restrict__ meta_g, u64* __restrict__ BT_g)
{
    __shared__ u16 npL[KMAX];
    const int tid = threadIdx.x;
    for (int k = tid; k < KMAX; k += 256) npL[k] = npl_g[k];
    u32 tail = meta_g[0];
    __syncthreads();
    int wseq = (blockIdx.x * 256 + tid) >> 6;   // wave id = t*KW + w
    int lane = tid & 63;
    int t = wseq / KW, w = wseq - t * KW;
    if (t >= (int)tail) return;
    int jt = npL[t];
    int s = w * 64 + lane;
    u32 ev = 0;
    if (s < (int)tail) {
        int is = npL[s];
        ev = (E[(size_t)is * NW + (jt >> 5)] >> (jt & 31)) & 1u;
    }
    u64 m = __ballot(ev != 0);
    if (lane == 0) BT_g[wseq] = m;
}

// ---- K4: upper-triangular transitive closure; dense chains + exact full-skip ----
__global__ __launch_bounds__(1024) void bfs_closure(
    const u64* __restrict__ BT_g, u64* __restrict__ A_g, const u32* __restrict__ meta_g)
{
    extern __shared__ u64 sm[];
    u64* A   = sm;                    // KMAX*AP  (66560 B)
    u64* BTL = A + KMAX * AP;         // KMAX*BTP (56320 B)

    const int tid  = threadIdx.x;
    const int lane = tid & 63;
    const int wid  = tid >> 6;
    const int tail = (int)meta_g[0];
    const int nb   = (tail + 63) >> 6;

    for (int r = tid; r < tail; r += 1024) {
        const u64* src = BT_g + (size_t)r * KW;
        u64* dst = BTL + (size_t)r * BTP;
        #pragma unroll
        for (int w = 0; w < KW; ++w) dst[w] = src[w];
    }
    for (int r = tid; r < tail; r += 1024) {
        u64* dst = A + (size_t)r * AP;
        #pragma unroll
        for (int w = 0; w < AP; ++w) dst[w] = (w == (r >> 6)) ? (1ull << (r & 63)) : 0ull;
    }
    __syncthreads();

    for (int p = 0; p < nb; ++p) {
        if (wid <= p) {
            // ---- near(block p-1 -> block p) + diag(block p), word wid ----
            __builtin_amdgcn_s_setprio(1);
            const int t = (p << 6) + lane;
            const bool valid = t < tail;
            u64 av = valid ? A[(size_t)t * AP + wid] : ~0ull;   // pad invalid with full
            if (wid < p && !__all(av == ~0ull)) {
                u64 asrc = A[(size_t)(((p - 1) << 6) + lane) * AP + wid];
                u64 xb = valid ? BTL[(size_t)t * BTP + (p - 1)] : 0ull;
                #pragma unroll 64
                for (int s = 0; s < 64; ++s)
                    av |= rdl64(asrc, s) & bitmask64(xb, s);
            }
            if (!__all(av == ~0ull)) {
                u64 xd = valid ? BTL[(size_t)t * BTP + p] : 0ull;
                xd &= (1ull << lane) - 1ull;              // only sources s < lane
                #pragma unroll 63
                for (int s = 0; s < 63; ++s)
                    av |= rdl64(av, s) & bitmask64(xd, s);
            }
            if (valid) A[(size_t)t * AP + wid] = av;
            __builtin_amdgcn_s_setprio(0);
        } else if (p >= 1) {
            // ---- far: dense chains, one (target-block, word) per chain; skip if full ----
            const int nbf = nb - 1 - p;
            const int C = p * nbf;
            const int nworkers = 15 - p;
            const int sb0 = (p - 1) << 6;
            for (int c = wid - p - 1; c < C; c += nworkers) {
                const int q = c / p;
                const int w = c - q * p;
                const int t = ((p + 1 + q) << 6) + lane;
                const bool valid = t < tail;
                u64 av = valid ? A[(size_t)t * AP + w] : ~0ull;
                if (!__all(av == ~0ull)) {
                    u64 asrc = A[(size_t)(sb0 + lane) * AP + w];
                    u64 x = valid ? BTL[(size_t)t * BTP + (p - 1)] : 0ull;
                    #pragma unroll 64
                    for (int s = 0; s < 64; ++s)
                        av |= rdl64(asrc, s) & bitmask64(x, s);
                    if (valid) A[(size_t)t * AP + w] = av;
                }
            }
        }
        __syncthreads();                               // one barrier per phase
    }

    for (int r = tid; r < tail; r += 1024) {
        const u64* src = A + (size_t)r * AP;
        u64* dst = A_g + (size_t)r * KW;
        #pragma unroll
        for (int w = 0; w < KW; ++w) dst[w] = src[w];
    }
}

// ---- K5: expand to f32 output (dag = E & masks & ~A) ----
__global__ __launch_bounds__(256) void final_expand(
    const u32* __restrict__ E, const u64* __restrict__ A_g,
    const u16* __restrict__ posof_g, const u32* __restrict__ meta_g,
    float4* __restrict__ out)
{
    int gid = blockIdx.x * 256 + threadIdx.x;
    int i = gid >> 8;
    int j0 = (gid & 255) << 2;
    u32 tail = meta_g[0];
    u32 pi = posof_g[i];
    float r[4] = {0.f, 0.f, 0.f, 0.f};
    if (pi == 0xFFFFu) {                              // root row: E & ~root
        u32 wv = E[(size_t)i * NW + (j0 >> 5)];
        #pragma unroll
        for (int t = 0; t < 4; ++t) {
            u32 pj = posof_g[j0 + t];
            bool nz = ((wv >> ((j0 & 31) + t)) & 1u) && (pj != 0xFFFFu);
            r[t] = nz ? 1.0f : 0.0f;
        }
    } else if (pi < tail) {                           // processed nonroot row
        const u64* Arow = A_g + (size_t)pi * KW;
        u32 wv = E[(size_t)i * NW + (j0 >> 5)];
        #pragma unroll
        for (int t = 0; t < 4; ++t) {
            u32 pj = posof_g[j0 + t];
            bool eb = (wv >> ((j0 & 31) + t)) & 1u;
            if (eb && pj != 0xFFFFu) {
                u64 ab = (pj < (u32)KMAX) ? Arow[pj >> 6] : 0ull;
                r[t] = ((ab >> (pj & 63)) & 1ull) ? 0.0f : 1.0f;
            }
        }
    }
    out[gid] = make_float4(r[0], r[1], r[2], r[3]);
}

extern "C" void kernel_launch(void* const* d_in, const int* in_sizes, int n_in,
                              void* d_out, int out_size, void* d_ws, size_t ws_size,
                              hipStream_t stream) {
    const float* root_probs = (const float*)d_in[0];
    const float* edge_probs = (const float*)d_in[1];
    const float* g_roots    = (const float*)d_in[2];
    const float* g_edges    = (const float*)d_in[3];

    char* ws = (char*)d_ws;
    u32* E       = (u32*)(ws);                 // 131072 B
    u64* BT_g    = (u64*)(ws + 131072);        // 51200 B
    u64* A_g     = (u64*)(ws + 182272);        // 51200 B
    u16* posof_g = (u16*)(ws + 233472);        // 2048 B
    u16* npl_g   = (u16*)(ws + 235520);        // 1280 B
    u32* meta_g  = (u32*)(ws + 236800);        // 64 B

    edge_bits_kernel<<<NN * NN / 256, 256, 0, stream>>>(edge_probs, g_edges, E);

    size_t lds_seed = (size_t)(NBIN * 16 + NBIN + 16 + 32) * 4;   // 69824 B
    hipFuncSetAttribute((const void*)seed_kernel,
                        hipFuncAttributeMaxDynamicSharedMemorySize, (int)lds_seed);
    seed_kernel<<<1, NN, lds_seed, stream>>>(root_probs, g_roots, E, meta_g, posof_g, npl_g);

    transposeB_kernel<<<KMAX * KW * 64 / 256, 256, 0, stream>>>(E, npl_g, meta_g, BT_g);

    size_t lds = (size_t)KMAX * AP * 8 + (size_t)KMAX * BTP * 8;   // 122880 B
    hipFuncSetAttribute((const void*)bfs_closure,
                        hipFuncAttributeMaxDynamicSharedMemorySize, (int)lds);
    bfs_closure<<<1, NN, lds, stream>>>(BT_g, A_g, meta_g);

    final_expand<<<NN * NN / 4 / 256, 256, 0, stream>>>(E, A_g, posof_g, meta_g,
                                                        (float4*)d_out);
}

// Round 19
// 62.046 us; speedup vs baseline: 4.3630x; 1.0142x over previous
//
#include <hip/hip_runtime.h>

#define NN 1024
#define NW 32            // u32 words per full 1024-bit row
#define KMAX 640         // max #non-roots (P(K>640) < 1e-14)
#define KW 10            // u64 words per compact row
#define AP  13           // A LDS row stride (u64), odd -> bank spread
#define BTP 11           // BT LDS row stride (u64), odd -> bank spread
#define NBIN 1024

typedef unsigned int u32;
typedef unsigned long long u64;
typedef unsigned short u16;

__device__ __forceinline__ u64 rdl64(u64 v, int s) {   // broadcast lane s (uniform s)
    u32 lo = (u32)__builtin_amdgcn_readlane((int)(u32)v, s);
    u32 hi = (u32)__builtin_amdgcn_readlane((int)(u32)(v >> 32), s);
    return ((u64)hi << 32) | (u64)lo;
}
__device__ __forceinline__ u64 bitmask64(u64 x, int s) {   // all-ones if bit s of x
    return (u64)(((long long)(x << (63 - s))) >> 63);
}

// ---- K1: edge hard bits -> E ----
__global__ void edge_bits_kernel(const float* __restrict__ ep, const float* __restrict__ ge,
                                 u32* __restrict__ E)
{
    int idx = blockIdx.x * blockDim.x + threadIdx.x;
    float p = ep[idx];
    float2 g = reinterpret_cast<const float2*>(ge)[idx];
    bool hard = (p + g.x) > ((1.0f - p) + g.y);
    u64 m = __ballot(hard);
    int lane = threadIdx.x & 63;
    if ((lane & 31) == 0) E[idx >> 5] = (u32)(m >> (lane & 32));
}

// ---- K2: roots + seed; pipelined root-row scan + histogram counting sort ----
__global__ __launch_bounds__(1024) void seed_kernel(
    const float* __restrict__ rp, const float* __restrict__ gr,
    const u32* __restrict__ Eg, u32* __restrict__ meta_g,
    u16* __restrict__ posof_g, u16* __restrict__ npl_g)
{
    extern __shared__ u32 sd[];
    u32* hist  = sd;                    // NBIN*16, layout [bin*16 + wave]
    u32* scan  = hist + NBIN * 16;      // NBIN (inclusive scan of totals)
    u32* wtot  = scan + NBIN;           // 16
    u32* rootm = wtot + 16;             // 32
    u16* rlist = (u16*)(rootm + 32);    // NN (root indices, ascending)

    const int tid = threadIdx.x;
    const int lane = tid & 63;
    const int wid  = tid >> 6;

    float p0 = rp[tid];
    float2 g0 = reinterpret_cast<const float2*>(gr)[tid];
    bool isroot = (p0 + g0.x) > ((1.0f - p0) + g0.y);
    u64 rm = __ballot(isroot);
    if (lane == 0) { rootm[wid * 2] = (u32)rm; rootm[wid * 2 + 1] = (u32)(rm >> 32); }
    for (int i = tid; i < NBIN * 16; i += 1024) hist[i] = 0u;
    __syncthreads();

    // per-thread roots-below count; build root list (ascending = root-rank order)
    int rb = 0, nroots = 0;
    {
        const int myw = tid >> 5;
        const u32 mybitm = (1u << (tid & 31)) - 1u;
        #pragma unroll
        for (int w = 0; w < 32; ++w) {
            u32 m = rootm[w];
            int pc = __popc(m);
            nroots += pc;
            rb += (myw > w) ? pc : ((myw == w) ? __popc(m & mybitm) : 0);
        }
    }
    if (isroot) rlist[rb] = (u16)tid;
    __syncthreads();

    // rank of first root hitting node tid — 4-wide pipelined L2 loads
    int fr = -1;
    if (!isroot) {
        const int mywd = tid >> 5;
        const u32 mybit = 1u << (tid & 31);
        for (int b = 0; b < nroots; b += 4) {
            u32 w0 = 0, w1 = 0, w2 = 0, w3 = 0;
            int n = nroots - b;
            w0 = Eg[(size_t)rlist[b] * NW + mywd];
            if (n > 1) w1 = Eg[(size_t)rlist[b + 1] * NW + mywd];
            if (n > 2) w2 = Eg[(size_t)rlist[b + 2] * NW + mywd];
            if (n > 3) w3 = Eg[(size_t)rlist[b + 3] * NW + mywd];
            if (fr < 0 && (w0 & mybit)) fr = b;
            if (fr < 0 && (w1 & mybit)) fr = b + 1;
            if (fr < 0 && (w2 & mybit)) fr = b + 2;
            if (fr < 0 && (w3 & mybit)) fr = b + 3;
            if (__all(fr >= 0)) break;
        }
    }
    bool found = (!isroot) && (fr >= 0);
    u32 ridx = found ? (u32)fr : 0xFFFFFFFFu;

    if (found) atomicAdd(&hist[ridx * 16 + wid], 1u);
    __syncthreads();

    u32 v;
    {
        const uint4* h4 = (const uint4*)(hist + tid * 16);
        uint4 a = h4[0], b = h4[1], c = h4[2], d = h4[3];
        v = a.x + a.y + a.z + a.w + b.x + b.y + b.z + b.w
          + c.x + c.y + c.z + c.w + d.x + d.y + d.z + d.w;
    }
    #pragma unroll
    for (int d2 = 1; d2 < 64; d2 <<= 1) {
        u32 u = (u32)__shfl_up((int)v, d2);
        if (lane >= d2) v += u;
    }
    if (lane == 63) wtot[wid] = v;
    __syncthreads();
    {
        u32 off = 0;
        #pragma unroll
        for (int w2 = 0; w2 < 16; ++w2) off += (w2 < wid) ? wtot[w2] : 0u;
        v += off;
        scan[tid] = v;
    }
    __syncthreads();

    int intra = 0;
    #pragma unroll 64
    for (int l2 = 0; l2 < 64; ++l2) {
        u32 rr = (u32)__builtin_amdgcn_readlane((int)ridx, l2);
        intra += (rr == ridx && l2 < lane) ? 1 : 0;
    }
    u32 pos = 0;
    if (found) {
        u32 base = (ridx > 0) ? scan[ridx - 1] : 0u;
        u32 wb = 0;
        for (int w = 0; w < wid; ++w) wb += hist[ridx * 16 + w];
        pos = base + wb + (u32)intra;
        if (pos < KMAX) npl_g[pos] = (u16)tid;
    }
    posof_g[tid] = isroot ? (u16)0xFFFF : (found ? (u16)pos : (u16)1023);
    if (tid == 0) {
        u32 tl = scan[NBIN - 1];
        meta_g[0] = (tl < (u32)KMAX) ? tl : (u32)KMAX;
    }
}

// ---- K3: BT via wave ballot — wave handles (t, w); lane s tests E[node(w*64+s)][node(t)] ----
__global__ __launch_bounds__(256) void transposeB_kernel(
    const u32* __restrict__ E, const u16* __restrict__ npl_g,
    const u32* __restrict__ meta_g, u64* __restrict__ BT_g)
{
    __shared__ u16 npL[KMAX];
    const int tid = threadIdx.x;
    for (int k = tid; k < KMAX; k += 256) npL[k] = npl_g[k];
    u32 tail = meta_g[0];
    __syncthreads();
    int wseq = (blockIdx.x * 256 + tid) >> 6;   // wave id = t*KW + w
    int lane = tid & 63;
    int t = wseq / KW, w = wseq - t * KW;
    if (t >= (int)tail) return;
    int jt = npL[t];
    int s = w * 64 + lane;
    u32 ev = 0;
    if (s < (int)tail) {
        int is = npL[s];
        ev = (E[(size_t)is * NW + (jt >> 5)] >> (jt & 31)) & 1u;
    }
    u64 m = __ballot(ev != 0);
    if (lane == 0) BT_g[wseq] = m;
}

// ---- K4: upper-triangular transitive closure; dense chains + exact full-skip ----
__global__ __launch_bounds__(1024) void bfs_closure(
    const u64* __restrict__ BT_g, u64* __restrict__ A_g, const u32* __restrict__ meta_g)
{
    extern __shared__ u64 sm[];
    u64* A   = sm;                    // KMAX*AP  (66560 B)
    u64* BTL = A + KMAX * AP;         // KMAX*BTP (56320 B)

    const int tid  = threadIdx.x;
    const int lane = tid & 63;
    const int wid  = tid >> 6;
    const int tail = (int)meta_g[0];
    const int nb   = (tail + 63) >> 6;

    for (int r = tid; r < tail; r += 1024) {
        const u64* src = BT_g + (size_t)r * KW;
        u64* dst = BTL + (size_t)r * BTP;
        #pragma unroll
        for (int w = 0; w < KW; ++w) dst[w] = src[w];
    }
    for (int r = tid; r < tail; r += 1024) {
        u64* dst = A + (size_t)r * AP;
        #pragma unroll
        for (int w = 0; w < AP; ++w) dst[w] = (w == (r >> 6)) ? (1ull << (r & 63)) : 0ull;
    }
    __syncthreads();

    for (int p = 0; p < nb; ++p) {
        if (wid <= p) {
            // ---- near(block p-1 -> block p) + diag(block p), word wid ----
            __builtin_amdgcn_s_setprio(1);
            const int t = (p << 6) + lane;
            const bool valid = t < tail;
            u64 av = valid ? A[(size_t)t * AP + wid] : ~0ull;   // pad invalid with full
            if (!__all(av == ~0ull)) {                          // whole tail conditional
                if (wid < p) {
                    u64 asrc = A[(size_t)(((p - 1) << 6) + lane) * AP + wid];
                    u64 xb = valid ? BTL[(size_t)t * BTP + (p - 1)] : 0ull;
                    #pragma unroll 64
                    for (int s = 0; s < 64; ++s)
                        av |= rdl64(asrc, s) & bitmask64(xb, s);
                }
                if (!__all(av == ~0ull)) {
                    u64 xd = valid ? BTL[(size_t)t * BTP + p] : 0ull;
                    xd &= (1ull << lane) - 1ull;              // only sources s < lane
                    #pragma unroll 63
                    for (int s = 0; s < 63; ++s)
                        av |= rdl64(av, s) & bitmask64(xd, s);
                }
                if (valid) A[(size_t)t * AP + wid] = av;
            }
            __builtin_amdgcn_s_setprio(0);
        } else if (p >= 1) {
            // ---- far: dense chains, one (target-block, word) per chain; skip if full ----
            const int nbf = nb - 1 - p;
            const int C = p * nbf;
            const int nworkers = 15 - p;
            const int sb0 = (p - 1) << 6;
            for (int c = wid - p - 1; c < C; c += nworkers) {
                const int q = c / p;
                const int w = c - q * p;
                const int t = ((p + 1 + q) << 6) + lane;
                const bool valid = t < tail;
                u64 av = valid ? A[(size_t)t * AP + w] : ~0ull;
                if (!__all(av == ~0ull)) {
                    u64 asrc = A[(size_t)(sb0 + lane) * AP + w];
                    u64 x = valid ? BTL[(size_t)t * BTP + (p - 1)] : 0ull;
                    #pragma unroll 64
                    for (int s = 0; s < 64; ++s)
                        av |= rdl64(asrc, s) & bitmask64(x, s);
                    if (valid) A[(size_t)t * AP + w] = av;
                }
            }
        }
        __syncthreads();                               // one barrier per phase
    }

    for (int r = tid; r < tail; r += 1024) {
        const u64* src = A + (size_t)r * AP;
        u64* dst = A_g + (size_t)r * KW;
        #pragma unroll
        for (int w = 0; w < KW; ++w) dst[w] = src[w];
    }
}

// ---- K5: expand to f32 output (dag = E & masks & ~A) ----
__global__ __launch_bounds__(256) void final_expand(
    const u32* __restrict__ E, const u64* __restrict__ A_g,
    const u16* __restrict__ posof_g, const u32* __restrict__ meta_g,
    float4* __restrict__ out)
{
    int gid = blockIdx.x * 256 + threadIdx.x;
    int i = gid >> 8;
    int j0 = (gid & 255) << 2;
    u32 tail = meta_g[0];
    u32 pi = posof_g[i];
    float r[4] = {0.f, 0.f, 0.f, 0.f};
    if (pi == 0xFFFFu) {                              // root row: E & ~root
        u32 wv = E[(size_t)i * NW + (j0 >> 5)];
        #pragma unroll
        for (int t = 0; t < 4; ++t) {
            u32 pj = posof_g[j0 + t];
            bool nz = ((wv >> ((j0 & 31) + t)) & 1u) && (pj != 0xFFFFu);
            r[t] = nz ? 1.0f : 0.0f;
        }
    } else if (pi < tail) {                           // processed nonroot row
        const u64* Arow = A_g + (size_t)pi * KW;
        u32 wv = E[(size_t)i * NW + (j0 >> 5)];
        #pragma unroll
        for (int t = 0; t < 4; ++t) {
            u32 pj = posof_g[j0 + t];
            bool eb = (wv >> ((j0 & 31) + t)) & 1u;
            if (eb && pj != 0xFFFFu) {
                u64 ab = (pj < (u32)KMAX) ? Arow[pj >> 6] : 0ull;
                r[t] = ((ab >> (pj & 63)) & 1ull) ? 0.0f : 1.0f;
            }
        }
    }
    out[gid] = make_float4(r[0], r[1], r[2], r[3]);
}

extern "C" void kernel_launch(void* const* d_in, const int* in_sizes, int n_in,
                              void* d_out, int out_size, void* d_ws, size_t ws_size,
                              hipStream_t stream) {
    const float* root_probs = (const float*)d_in[0];
    const float* edge_probs = (const float*)d_in[1];
    const float* g_roots    = (const float*)d_in[2];
    const float* g_edges    = (const float*)d_in[3];

    char* ws = (char*)d_ws;
    u32* E       = (u32*)(ws);                 // 131072 B
    u64* BT_g    = (u64*)(ws + 131072);        // 51200 B
    u64* A_g     = (u64*)(ws + 182272);        // 51200 B
    u16* posof_g = (u16*)(ws + 233472);        // 2048 B
    u16* npl_g   = (u16*)(ws + 235520);        // 1280 B
    u32* meta_g  = (u32*)(ws + 236800);        // 64 B

    edge_bits_kernel<<<NN * NN / 256, 256, 0, stream>>>(edge_probs, g_edges, E);

    size_t lds_seed = (size_t)(NBIN * 16 + NBIN + 16 + 32) * 4 + NN * 2;   // 71872 B
    hipFuncSetAttribute((const void*)seed_kernel,
                        hipFuncAttributeMaxDynamicSharedMemorySize, (int)lds_seed);
    seed_kernel<<<1, NN, lds_seed, stream>>>(root_probs, g_roots, E, meta_g, posof_g, npl_g);

    transposeB_kernel<<<KMAX * KW * 64 / 256, 256, 0, stream>>>(E, npl_g, meta_g, BT_g);

    size_t lds = (size_t)KMAX * AP * 8 + (size_t)KMAX * BTP * 8;   // 122880 B
    hipFuncSetAttribute((const void*)bfs_closure,
                        hipFuncAttributeMaxDynamicSharedMemorySize, (int)lds);
    bfs_closure<<<1, NN, lds, stream>>>(BT_g, A_g, meta_g);

    final_expand<<<NN * NN / 4 / 256, 256, 0, stream>>>(E, A_g, posof_g, meta_g,
                                                        (float4*)d_out);
}

// Round 20
// 61.608 us; speedup vs baseline: 4.3940x; 1.0071x over previous
//
#include <hip/hip_runtime.h>

#define NN 1024
#define NW 32            // u32 words per full 1024-bit row
#define KMAX 640         // max #non-roots (P(K>640) < 1e-14)
#define KW 10            // u64 words per compact row
#define AP  13           // A LDS row stride (u64), odd -> bank spread
#define BTP 11           // BT LDS row stride (u64), odd -> bank spread
#define NBIN 1024

typedef unsigned int u32;
typedef unsigned long long u64;
typedef unsigned short u16;

__device__ __forceinline__ u64 rdl64(u64 v, int s) {   // broadcast lane s (uniform s)
    u32 lo = (u32)__builtin_amdgcn_readlane((int)(u32)v, s);
    u32 hi = (u32)__builtin_amdgcn_readlane((int)(u32)(v >> 32), s);
    return ((u64)hi << 32) | (u64)lo;
}
__device__ __forceinline__ u64 bitmask64(u64 x, int s) {   // all-ones if bit s of x
    return (u64)(((long long)(x << (63 - s))) >> 63);
}

// ---- K1: edge hard bits -> E ; 4 elements/thread (strided 64 in a 256-elem wave tile) ----
__global__ __launch_bounds__(256) void edge_bits_kernel(
    const float* __restrict__ ep, const float* __restrict__ ge, u32* __restrict__ E)
{
    const int lane = threadIdx.x & 63;
    const int wavebase = blockIdx.x * 1024 + (threadIdx.x >> 6) * 256;
    #pragma unroll
    for (int k = 0; k < 4; ++k) {
        int e = wavebase + k * 64 + lane;
        float p = ep[e];
        float2 g = reinterpret_cast<const float2*>(ge)[e];
        bool hard = (p + g.x) > ((1.0f - p) + g.y);
        u64 m = __ballot(hard);
        if ((lane & 31) == 0)
            E[(wavebase >> 5) + k * 2 + (lane >> 5)] = (u32)(m >> (lane & 32));
    }
}

// ---- K2: roots + seed; pipelined root-row scan + histogram counting sort ----
__global__ __launch_bounds__(1024) void seed_kernel(
    const float* __restrict__ rp, const float* __restrict__ gr,
    const u32* __restrict__ Eg, u32* __restrict__ meta_g,
    u16* __restrict__ posof_g, u16* __restrict__ npl_g)
{
    extern __shared__ u32 sd[];
    u32* hist  = sd;                    // NBIN*16, layout [bin*16 + wave]
    u32* scan  = hist + NBIN * 16;      // NBIN (inclusive scan of totals)
    u32* wtot  = scan + NBIN;           // 16
    u32* rootm = wtot + 16;             // 32
    u16* rlist = (u16*)(rootm + 32);    // NN (root indices, ascending)

    const int tid = threadIdx.x;
    const int lane = tid & 63;
    const int wid  = tid >> 6;

    float p0 = rp[tid];
    float2 g0 = reinterpret_cast<const float2*>(gr)[tid];
    bool isroot = (p0 + g0.x) > ((1.0f - p0) + g0.y);
    u64 rm = __ballot(isroot);
    if (lane == 0) { rootm[wid * 2] = (u32)rm; rootm[wid * 2 + 1] = (u32)(rm >> 32); }
    {
        u64* h64 = (u64*)hist;
        for (int i = tid; i < NBIN * 8; i += 1024) h64[i] = 0ull;
    }
    __syncthreads();

    // per-thread roots-below count; build root list (ascending = root-rank order)
    int rb = 0, nroots = 0;
    {
        const int myw = tid >> 5;
        const u32 mybitm = (1u << (tid & 31)) - 1u;
        #pragma unroll
        for (int w = 0; w < 32; ++w) {
            u32 m = rootm[w];
            int pc = __popc(m);
            nroots += pc;
            rb += (myw > w) ? pc : ((myw == w) ? __popc(m & mybitm) : 0);
        }
    }
    if (isroot) rlist[rb] = (u16)tid;
    __syncthreads();

    // rank of first root hitting node tid — 4-wide pipelined L2 loads
    int fr = -1;
    if (!isroot) {
        const int mywd = tid >> 5;
        const u32 mybit = 1u << (tid & 31);
        for (int b = 0; b < nroots; b += 4) {
            u32 w0 = 0, w1 = 0, w2 = 0, w3 = 0;
            int n = nroots - b;
            w0 = Eg[(size_t)rlist[b] * NW + mywd];
            if (n > 1) w1 = Eg[(size_t)rlist[b + 1] * NW + mywd];
            if (n > 2) w2 = Eg[(size_t)rlist[b + 2] * NW + mywd];
            if (n > 3) w3 = Eg[(size_t)rlist[b + 3] * NW + mywd];
            if (fr < 0 && (w0 & mybit)) fr = b;
            if (fr < 0 && (w1 & mybit)) fr = b + 1;
            if (fr < 0 && (w2 & mybit)) fr = b + 2;
            if (fr < 0 && (w3 & mybit)) fr = b + 3;
            if (__all(fr >= 0)) break;
        }
    }
    bool found = (!isroot) && (fr >= 0);
    u32 ridx = found ? (u32)fr : 0xFFFFFFFFu;

    if (found) atomicAdd(&hist[ridx * 16 + wid], 1u);
    __syncthreads();

    u32 v;
    {
        const uint4* h4 = (const uint4*)(hist + tid * 16);
        uint4 a = h4[0], b = h4[1], c = h4[2], d = h4[3];
        v = a.x + a.y + a.z + a.w + b.x + b.y + b.z + b.w
          + c.x + c.y + c.z + c.w + d.x + d.y + d.z + d.w;
    }
    #pragma unroll
    for (int d2 = 1; d2 < 64; d2 <<= 1) {
        u32 u = (u32)__shfl_up((int)v, d2);
        if (lane >= d2) v += u;
    }
    if (lane == 63) wtot[wid] = v;
    __syncthreads();
    {
        u32 off = 0;
        #pragma unroll
        for (int w2 = 0; w2 < 16; ++w2) off += (w2 < wid) ? wtot[w2] : 0u;
        v += off;
        scan[tid] = v;
    }
    __syncthreads();

    int intra = 0;
    #pragma unroll 64
    for (int l2 = 0; l2 < 64; ++l2) {
        u32 rr = (u32)__builtin_amdgcn_readlane((int)ridx, l2);
        intra += (rr == ridx && l2 < lane) ? 1 : 0;
    }
    u32 pos = 0;
    if (found) {
        u32 base = (ridx > 0) ? scan[ridx - 1] : 0u;
        u32 wb = 0;
        for (int w = 0; w < wid; ++w) wb += hist[ridx * 16 + w];
        pos = base + wb + (u32)intra;
        if (pos < KMAX) npl_g[pos] = (u16)tid;
    }
    posof_g[tid] = isroot ? (u16)0xFFFF : (found ? (u16)pos : (u16)1023);
    if (tid == 0) {
        u32 tl = scan[NBIN - 1];
        meta_g[0] = (tl < (u32)KMAX) ? tl : (u32)KMAX;
    }
}

// ---- K3: BT via wave ballot — wave handles (t, w); lane s tests E[node(w*64+s)][node(t)] ----
__global__ __launch_bounds__(256) void transposeB_kernel(
    const u32* __restrict__ E, const u16* __restrict__ npl_g,
    const u32* __restrict__ meta_g, u64* __restrict__ BT_g)
{
    __shared__ u16 npL[KMAX];
    const int tid = threadIdx.x;
    for (int k = tid; k < KMAX; k += 256) npL[k] = npl_g[k];
    u32 tail = meta_g[0];
    __syncthreads();
    int wseq = (blockIdx.x * 256 + tid) >> 6;   // wave id = t*KW + w
    int lane = tid & 63;
    int t = wseq / KW, w = wseq - t * KW;
    if (t >= (int)tail) return;
    int jt = npL[t];
    int s = w * 64 + lane;
    u32 ev = 0;
    if (s < (int)tail) {
        int is = npL[s];
        ev = (E[(size_t)is * NW + (jt >> 5)] >> (jt & 31)) & 1u;
    }
    u64 m = __ballot(ev != 0);
    if (lane == 0) BT_g[wseq] = m;
}

// ---- K4: upper-triangular transitive closure; dense chains + exact full-skip ----
__global__ __launch_bounds__(1024) void bfs_closure(
    const u64* __restrict__ BT_g, u64* __restrict__ A_g, const u32* __restrict__ meta_g)
{
    extern __shared__ u64 sm[];
    u64* A   = sm;                    // KMAX*AP  (66560 B)
    u64* BTL = A + KMAX * AP;         // KMAX*BTP (56320 B)

    const int tid  = threadIdx.x;
    const int lane = tid & 63;
    const int wid  = tid >> 6;
    const int tail = (int)meta_g[0];
    const int nb   = (tail + 63) >> 6;

    for (int r = tid; r < tail; r += 1024) {
        const u64* src = BT_g + (size_t)r * KW;
        u64* dst = BTL + (size_t)r * BTP;
        #pragma unroll
        for (int w = 0; w < KW; ++w) dst[w] = src[w];
    }
    for (int r = tid; r < tail; r += 1024) {
        u64* dst = A + (size_t)r * AP;
        #pragma unroll
        for (int w = 0; w < AP; ++w) dst[w] = (w == (r >> 6)) ? (1ull << (r & 63)) : 0ull;
    }
    __syncthreads();

    for (int p = 0; p < nb; ++p) {
        if (wid <= p) {
            // ---- near(block p-1 -> block p) + diag(block p), word wid ----
            __builtin_amdgcn_s_setprio(1);
            const int t = (p << 6) + lane;
            const bool valid = t < tail;
            u64 av = valid ? A[(size_t)t * AP + wid] : ~0ull;   // pad invalid with full
            if (!__all(av == ~0ull)) {                          // exact full-skip
                if (wid < p) {
                    u64 asrc = A[(size_t)(((p - 1) << 6) + lane) * AP + wid];
                    u64 xb = valid ? BTL[(size_t)t * BTP + (p - 1)] : 0ull;
                    #pragma unroll 64
                    for (int s = 0; s < 64; ++s)
                        av |= rdl64(asrc, s) & bitmask64(xb, s);
                }
                if (!__all(av == ~0ull)) {
                    u64 xd = valid ? BTL[(size_t)t * BTP + p] : 0ull;
                    xd &= (1ull << lane) - 1ull;              // only sources s < lane
                    #pragma unroll 63
                    for (int s = 0; s < 63; ++s)
                        av |= rdl64(av, s) & bitmask64(xd, s);
                }
                if (valid) A[(size_t)t * AP + wid] = av;
            }
            __builtin_amdgcn_s_setprio(0);
        } else if (p >= 1) {
            // ---- far: dense chains word-major; cache asrc across same-word chains ----
            const int nbf = nb - 1 - p;
            const int C = p * nbf;
            const int nworkers = 15 - p;
            const int sb0 = (p - 1) << 6;
            int lastw = -1;
            u64 asrc = 0;
            for (int c = wid - p - 1; c < C; c += nworkers) {
                const int w = c / nbf;
                const int q = c - w * nbf;
                const int t = ((p + 1 + q) << 6) + lane;
                const bool valid = t < tail;
                u64 av = valid ? A[(size_t)t * AP + w] : ~0ull;
                if (!__all(av == ~0ull)) {
                    if (w != lastw) { asrc = A[(size_t)(sb0 + lane) * AP + w]; lastw = w; }
                    u64 x = valid ? BTL[(size_t)t * BTP + (p - 1)] : 0ull;
                    #pragma unroll 64
                    for (int s = 0; s < 64; ++s)
                        av |= rdl64(asrc, s) & bitmask64(x, s);
                    if (valid) A[(size_t)t * AP + w] = av;
                }
            }
        }
        __syncthreads();                               // one barrier per phase
    }

    for (int r = tid; r < tail; r += 1024) {
        const u64* src = A + (size_t)r * AP;
        u64* dst = A_g + (size_t)r * KW;
        #pragma unroll
        for (int w = 0; w < KW; ++w) dst[w] = src[w];
    }
}

// ---- K5: expand to f32 output (dag = E & masks & ~A) ----
__global__ __launch_bounds__(256) void final_expand(
    const u32* __restrict__ E, const u64* __restrict__ A_g,
    const u16* __restrict__ posof_g, const u32* __restrict__ meta_g,
    float4* __restrict__ out)
{
    int gid = blockIdx.x * 256 + threadIdx.x;
    int i = gid >> 8;
    int j0 = (gid & 255) << 2;
    u32 tail = meta_g[0];
    u32 pi = posof_g[i];
    float r[4] = {0.f, 0.f, 0.f, 0.f};
    if (pi == 0xFFFFu) {                              // root row: E & ~root
        u32 wv = E[(size_t)i * NW + (j0 >> 5)];
        #pragma unroll
        for (int t = 0; t < 4; ++t) {
            u32 pj = posof_g[j0 + t];
            bool nz = ((wv >> ((j0 & 31) + t)) & 1u) && (pj != 0xFFFFu);
            r[t] = nz ? 1.0f : 0.0f;
        }
    } else if (pi < tail) {                           // processed nonroot row
        const u64* Arow = A_g + (size_t)pi * KW;
        u32 wv = E[(size_t)i * NW + (j0 >> 5)];
        #pragma unroll
        for (int t = 0; t < 4; ++t) {
            u32 pj = posof_g[j0 + t];
            bool eb = (wv >> ((j0 & 31) + t)) & 1u;
            if (eb && pj != 0xFFFFu) {
                u64 ab = (pj < (u32)KMAX) ? Arow[pj >> 6] : 0ull;
                r[t] = ((ab >> (pj & 63)) & 1ull) ? 0.0f : 1.0f;
            }
        }
    }
    out[gid] = make_float4(r[0], r[1], r[2], r[3]);
}

extern "C" void kernel_launch(void* const* d_in, const int* in_sizes, int n_in,
                              void* d_out, int out_size, void* d_ws, size_t ws_size,
                              hipStream_t stream) {
    const float* root_probs = (const float*)d_in[0];
    const float* edge_probs = (const float*)d_in[1];
    const float* g_roots    = (const float*)d_in[2];
    const float* g_edges    = (const float*)d_in[3];

    char* ws = (char*)d_ws;
    u32* E       = (u32*)(ws);                 // 131072 B
    u64* BT_g    = (u64*)(ws + 131072);        // 51200 B
    u64* A_g     = (u64*)(ws + 182272);        // 51200 B
    u16* posof_g = (u16*)(ws + 233472);        // 2048 B
    u16* npl_g   = (u16*)(ws + 235520);        // 1280 B
    u32* meta_g  = (u32*)(ws + 236800);        // 64 B

    edge_bits_kernel<<<NN * NN / 1024, 256, 0, stream>>>(edge_probs, g_edges, E);

    size_t lds_seed = (size_t)(NBIN * 16 + NBIN + 16 + 32) * 4 + NN * 2;   // 71872 B
    hipFuncSetAttribute((const void*)seed_kernel,
                        hipFuncAttributeMaxDynamicSharedMemorySize, (int)lds_seed);
    seed_kernel<<<1, NN, lds_seed, stream>>>(root_probs, g_roots, E, meta_g, posof_g, npl_g);

    transposeB_kernel<<<KMAX * KW * 64 / 256, 256, 0, stream>>>(E, npl_g, meta_g, BT_g);

    size_t lds = (size_t)KMAX * AP * 8 + (size_t)KMAX * BTP * 8;   // 122880 B
    hipFuncSetAttribute((const void*)bfs_closure,
                        hipFuncAttributeMaxDynamicSharedMemorySize, (int)lds);
    bfs_closure<<<1, NN, lds, stream>>>(BT_g, A_g, meta_g);

    final_expand<<<NN * NN / 4 / 256, 256, 0, stream>>>(E, A_g, posof_g, meta_g,
                                                        (float4*)d_out);
}